// Round 7
// baseline (174.467 us; speedup 1.0000x reference)
//
#include <hip/hip_runtime.h>

typedef __bf16 bf16;
typedef __bf16 bf16x8 __attribute__((ext_vector_type(8)));
typedef __bf16 bf16x4 __attribute__((ext_vector_type(4)));
typedef float f32x4 __attribute__((ext_vector_type(4)));
typedef float f32x16 __attribute__((ext_vector_type(16)));

// x: [256][4096] f32, conv_w: [1536][256] f32, out: [512][4096] f32
// heads=8; channels per head: key [0:64), query [64:128), value [128:192)
// qkvT per head (786432): [QT(query) [4096][64] | KT(key) [4096][64] | V [64][4096]]
// k_conv stores RAW (pre-norm) bf16. Q/K GroupNorm affine applied inside k_attn
// (Q at frag load with log2(e)/8 folded; K at LDS staging). V affine folds into
// k_final: out = a_v*(sum O)/(sum L) + b_v.

#define QF 0.18033688011112042f   // log2(e)/8

// ---------------- K_misc: xpose + cast_w + zero(cs) ----------------
__global__ void k_misc(const float* __restrict__ x, const float* __restrict__ w,
                       bf16* __restrict__ xT, bf16* __restrict__ wb, float* __restrict__ cs) {
    int b = blockIdx.x;
    if (b < 512) {
        int t = b * 256 + threadIdx.x;
        int p  = t & 4095;
        int c0 = (t >> 12) * 8;
        bf16x8 o;
#pragma unroll
        for (int j = 0; j < 8; j++) o[j] = (bf16)x[(c0 + j) * 4096 + p];
        *(bf16x8*)(xT + p * 256 + c0) = o;
    } else if (b < 896) {
        int idx = ((b - 512) * 256 + threadIdx.x) * 4;
        float4 f = *(const float4*)(w + idx);
        bf16x4 o;
        o[0] = (bf16)f.x; o[1] = (bf16)f.y; o[2] = (bf16)f.z; o[3] = (bf16)f.w;
        *(bf16x4*)(wb + idx) = o;
    } else {
#pragma unroll
        for (int i = 0; i < 12; i++) cs[i * 256 + threadIdx.x] = 0.f;
    }
}

// ---------------- K1: conv GEMM -> stats + LDS-transposed coalesced stores ----------------
__global__ __launch_bounds__(256) void k_conv(const bf16* __restrict__ Wb,
                                              const bf16* __restrict__ xT,
                                              bf16* __restrict__ qkvT,
                                              float* __restrict__ cs) {
    __shared__ __attribute__((aligned(16))) bf16 tile[64 * 72];
    int wid = threadIdx.x >> 6, lane = threadIdx.x & 63;
    int quad = lane >> 4, l15 = lane & 15;
    int g  = blockIdx.x % 24;
    int pb = (blockIdx.x / 24) * 64;
    int h = g / 3, sec = g % 3;          // 0=key 1=query 2=value
    int ob = g * 64;
    int orow = ob + wid * 16 + l15;

    f32x4 acc[4];
#pragma unroll
    for (int c = 0; c < 4; c++) acc[c] = (f32x4){0.f, 0.f, 0.f, 0.f};

#pragma unroll
    for (int ks = 0; ks < 8; ks++) {
        bf16x8 a = *(const bf16x8*)(Wb + orow * 256 + ks * 32 + quad * 8);
#pragma unroll
        for (int c = 0; c < 4; c++) {
            bf16x8 b = *(const bf16x8*)(xT + (pb + c * 16 + l15) * 256 + ks * 32 + quad * 8);
            acc[c] = __builtin_amdgcn_mfma_f32_16x16x32_bf16(a, b, acc[c], 0, 0, 0);
        }
    }

    int ch0 = wid * 16 + quad * 4;
#pragma unroll
    for (int r = 0; r < 4; r++) {
        float sp  = acc[0][r] + acc[1][r] + acc[2][r] + acc[3][r];
        float ssp = acc[0][r] * acc[0][r] + acc[1][r] * acc[1][r]
                  + acc[2][r] * acc[2][r] + acc[3][r] * acc[3][r];
#pragma unroll
        for (int m = 1; m < 16; m <<= 1) {
            sp  += __shfl_xor(sp,  m, 64);
            ssp += __shfl_xor(ssp, m, 64);
        }
        if (l15 == 0) {
            atomicAdd(cs + (ob + ch0 + r) * 2,     sp);
            atomicAdd(cs + (ob + ch0 + r) * 2 + 1, ssp);
        }
    }

    if (sec == 2) {                      // V wants [ch][px]
#pragma unroll
        for (int c = 0; c < 4; c++)
#pragma unroll
            for (int r = 0; r < 4; r++)
                tile[(ch0 + r) * 72 + c * 16 + l15] = (bf16)acc[c][r];
    } else {                             // Q/K want [px][ch]
#pragma unroll
        for (int c = 0; c < 4; c++) {
            bf16x4 o;
#pragma unroll
            for (int r = 0; r < 4; r++) o[r] = (bf16)acc[c][r];
            *(bf16x4*)(&tile[(c * 16 + l15) * 72 + ch0]) = o;
        }
    }
    __syncthreads();
    bf16* base = qkvT + h * 786432;
    int t = threadIdx.x;
    if (sec == 2) {
        bf16* V = base + 524288;
#pragma unroll
        for (int it = 0; it < 2; it++) {
            int e = it * 256 + t; int ch = e >> 3; int pxo = (e & 7) * 8;
            *(bf16x8*)(V + ch * 4096 + pb + pxo) = *(const bf16x8*)(&tile[ch * 72 + pxo]);
        }
    } else {
        bf16* dst = base + (sec == 0 ? 262144 : 0);
#pragma unroll
        for (int it = 0; it < 2; it++) {
            int e = it * 256 + t; int px = e >> 3; int cho = (e & 7) * 8;
            *(bf16x8*)(dst + (pb + px) * 64 + cho) = *(const bf16x8*)(&tile[px * 72 + cho]);
        }
    }
}

// ---------------- K2: flash attention, 32x32x16 MFMA, P via half-wave swizzle ----------------
// grid 512 = 8 heads x 16 q-blocks(256q) x 4 L-splits; wave owns 64 q.
__global__ __launch_bounds__(256, 2) void k_attn(const bf16* __restrict__ qkvT,
                                                 const float2* __restrict__ cs,
                                                 const float* __restrict__ gnw,
                                                 const float* __restrict__ gnb,
                                                 bf16* __restrict__ Opart,
                                                 float* __restrict__ Lsum) {
    int bid   = blockIdx.x;
    int h     = bid & 7;                  // XCD L2 affinity
    int qb    = (bid >> 3) & 15;
    int split = bid >> 7;                 // 0..3
    int wid = threadIdx.x >> 6, lane = threadIdx.x & 63;
    int l31 = lane & 31, half = lane >> 5;
    const bf16* QT = qkvT + h * 786432;
    const bf16* KT = QT + 262144;
    const bf16* V  = QT + 524288;
    int qw = qb * 256 + wid * 64;

    __shared__ __attribute__((aligned(16))) bf16 Ks[64 * 72];
    __shared__ __attribute__((aligned(16))) bf16 Vs[64 * 72];

    // ---- inline group stats for Q (g=h*3+1) and K (g=h*3+0) ----
    float2 vq = cs[(h * 3 + 1) * 64 + lane];
    float2 vk = cs[(h * 3 + 0) * 64 + lane];
    float sq = vq.x, ssq = vq.y, sk = vk.x, ssk = vk.y;
#pragma unroll
    for (int m = 1; m < 64; m <<= 1) {
        sq += __shfl_xor(sq, m, 64); ssq += __shfl_xor(ssq, m, 64);
        sk += __shfl_xor(sk, m, 64); ssk += __shfl_xor(ssk, m, 64);
    }
    const float N = 262144.0f;
    float mq = sq / N, iq = rsqrtf(ssq / N - mq * mq + 1e-5f);
    float mk = sk / N, ik = rsqrtf(ssk / N - mk * mk + 1e-5f);

    // ---- staging-channel K affine consts ----
    int r0   = threadIdx.x >> 3;          // staging rows r0 and r0+32
    int koff = (threadIdx.x & 7) * 8;
    float akc[8], bkc[8];
#pragma unroll
    for (int j = 0; j < 8; j++) {
        float gw = gnw[h * 192 + koff + j];
        akc[j] = ik * gw;
        bkc[j] = gnb[h * 192 + koff + j] - mk * akc[j];
    }

    // ---- Q B-fragments with affine (loop-invariant): B[n=q][k=kd] ----
    bf16x8 bq[2][4];
#pragma unroll
    for (int ks = 0; ks < 4; ks++) {
        float aqc[8], bqc[8];
#pragma unroll
        for (int j = 0; j < 8; j++) {
            int ch = h * 192 + 64 + ks * 16 + half * 8 + j;
            float gw = gnw[ch];
            aqc[j] = iq * gw * QF;
            bqc[j] = (gnb[ch] - mq * iq * gw) * QF;
        }
#pragma unroll
        for (int qs = 0; qs < 2; qs++) {
            bf16x8 raw = *(const bf16x8*)(QT + (qw + qs * 32 + l31) * 64 + ks * 16 + half * 8);
            bf16x8 o;
#pragma unroll
            for (int j = 0; j < 8; j++) o[j] = (bf16)(aqc[j] * (float)raw[j] + bqc[j]);
            bq[qs][ks] = o;
        }
    }

    f32x16 oacc[2][2];                    // [kd-block][qs]
#pragma unroll
    for (int kb = 0; kb < 2; kb++)
#pragma unroll
        for (int qs = 0; qs < 2; qs++) oacc[kb][qs] = (f32x16)(0.0f);
    float ls[2] = {0.f, 0.f};

    int t0 = split * 16, t1 = t0 + 16;

    // prefetch tile t0 into registers
    bf16x8 kf0, kf1, vf0, vf1;
    {
        int lb0 = t0 * 64;
        kf0 = *(const bf16x8*)(KT + (lb0 + r0) * 64 + koff);
        kf1 = *(const bf16x8*)(KT + (lb0 + r0 + 32) * 64 + koff);
        vf0 = *(const bf16x8*)(V + r0 * 4096 + lb0 + koff);
        vf1 = *(const bf16x8*)(V + (r0 + 32) * 4096 + lb0 + koff);
    }

    union U4 { bf16x4 v; unsigned int u[2]; };

    for (int lt = t0; lt < t1; lt++) {
        __syncthreads();
        {
            bf16x8 k0, k1;
#pragma unroll
            for (int j = 0; j < 8; j++) {
                k0[j] = (bf16)(akc[j] * (float)kf0[j] + bkc[j]);
                k1[j] = (bf16)(akc[j] * (float)kf1[j] + bkc[j]);
            }
            *(bf16x8*)(Ks + r0 * 72 + koff)        = k0;
            *(bf16x8*)(Ks + (r0 + 32) * 72 + koff) = k1;
            *(bf16x8*)(Vs + r0 * 72 + koff)        = vf0;
            *(bf16x8*)(Vs + (r0 + 32) * 72 + koff) = vf1;
        }
        __syncthreads();

        if (lt + 1 < t1) {
            int nb = (lt + 1) * 64;
            kf0 = *(const bf16x8*)(KT + (nb + r0) * 64 + koff);
            kf1 = *(const bf16x8*)(KT + (nb + r0 + 32) * 64 + koff);
            vf0 = *(const bf16x8*)(V + r0 * 4096 + nb + koff);
            vf1 = *(const bf16x8*)(V + (r0 + 32) * 4096 + nb + koff);
        }

        // K A-frags: A[m=l][k=kd]; V A-frags: A[m=kd][k=l]  (16B contiguous reads)
        bf16x8 ak[2][4], av[2][4];
#pragma unroll
        for (int ksx = 0; ksx < 4; ksx++)
#pragma unroll
            for (int b2 = 0; b2 < 2; b2++) {
                ak[b2][ksx] = *(const bf16x8*)(Ks + (b2 * 32 + l31) * 72 + ksx * 16 + half * 8);
                av[b2][ksx] = *(const bf16x8*)(Vs + (b2 * 32 + l31) * 72 + ksx * 16 + half * 8);
            }

#pragma unroll
        for (int qs = 0; qs < 2; qs++) {
            // S^T = K·Q : two 32x32 C-tiles (lb=0,1), col = q = lane&31
            f32x16 s0 = (f32x16)(0.0f), s1 = (f32x16)(0.0f);
#pragma unroll
            for (int ks = 0; ks < 4; ks++) {
                s0 = __builtin_amdgcn_mfma_f32_32x32x16_bf16(ak[0][ks], bq[qs][ks], s0, 0, 0, 0);
                s1 = __builtin_amdgcn_mfma_f32_32x32x16_bf16(ak[1][ks], bq[qs][ks], s1, 0, 0, 0);
            }
            // P = exp2, denominator in-lane (all regs share col q)
            float e0[16], e1[16];
#pragma unroll
            for (int i = 0; i < 16; i++) { e0[i] = __builtin_amdgcn_exp2f(s0[i]); ls[qs] += e0[i]; }
#pragma unroll
            for (int i = 0; i < 16; i++) { e1[i] = __builtin_amdgcn_exp2f(s1[i]); ls[qs] += e1[i]; }

            // C->B-frag: regs r..r+3 are l=(r&3)+8*(r>>2)+4*half; exchange with lane^32
            bf16x8 pf[4];
#pragma unroll
            for (int gp = 0; gp < 4; gp++) {       // gp = ksl group (0,1 from s0; 2,3 from s1)
                const float* e = (gp < 2) ? (gp & 1 ? e1 - 8 : e0) : (gp & 1 ? e1 : e0);
                // select: gp0->e0[0..7], gp1->e0[8..15], gp2->e1[0..7], gp3->e1[8..15]
                const float* eb = (gp == 0) ? e0 : (gp == 1) ? e0 + 8 : (gp == 2) ? e1 : e1 + 8;
                U4 lo4, hi4;
                lo4.v[0] = (bf16)eb[0]; lo4.v[1] = (bf16)eb[1];
                lo4.v[2] = (bf16)eb[2]; lo4.v[3] = (bf16)eb[3];
                hi4.v[0] = (bf16)eb[4]; hi4.v[1] = (bf16)eb[5];
                hi4.v[2] = (bf16)eb[6]; hi4.v[3] = (bf16)eb[7];
                unsigned int xlo0 = (unsigned int)__shfl_xor((int)lo4.u[0], 32, 64);
                unsigned int xlo1 = (unsigned int)__shfl_xor((int)lo4.u[1], 32, 64);
                unsigned int xhi0 = (unsigned int)__shfl_xor((int)hi4.u[0], 32, 64);
                unsigned int xhi1 = (unsigned int)__shfl_xor((int)hi4.u[1], 32, 64);
                union { bf16x8 v; unsigned int u[4]; } f;
                // lo lane: [own lo4 | partner lo4]; hi lane: [partner hi4 | own hi4]
                f.u[0] = half ? xhi0 : lo4.u[0];
                f.u[1] = half ? xhi1 : lo4.u[1];
                f.u[2] = half ? hi4.u[0] : xlo0;
                f.u[3] = half ? hi4.u[1] : xlo1;
                pf[gp] = f.v;
            }
            // O[kd][q] += V·P
#pragma unroll
            for (int ksl = 0; ksl < 4; ksl++) {
                oacc[0][qs] = __builtin_amdgcn_mfma_f32_32x32x16_bf16(av[0][ksl], pf[ksl], oacc[0][qs], 0, 0, 0);
                oacc[1][qs] = __builtin_amdgcn_mfma_f32_32x32x16_bf16(av[1][ksl], pf[ksl], oacc[1][qs], 0, 0, 0);
            }
        }
    }

    // denominators: halves hold complementary l-rows of col q
#pragma unroll
    for (int qs = 0; qs < 2; qs++) {
        ls[qs] += __shfl_xor(ls[qs], 32, 64);
        if (half == 0)
            Lsum[split * 32768 + h * 4096 + qw + qs * 32 + l31] = ls[qs];
    }

    // partial O (unnormalized, bf16): row = h*64+kd, col = q
    bf16* Ob = Opart + split * 2097152;
#pragma unroll
    for (int kb = 0; kb < 2; kb++)
#pragma unroll
        for (int qs = 0; qs < 2; qs++)
#pragma unroll
            for (int r = 0; r < 16; r++) {
                int kd = kb * 32 + (r & 3) + 8 * (r >> 2) + 4 * half;
                Ob[(h * 64 + kd) * 4096 + qw + qs * 32 + l31] = (bf16)oacc[kb][qs][r];
            }
}

// ---------------- K3: combine 4 splits + V affine (stats inline) + normalize ----------------
__global__ void k_final(const bf16* __restrict__ Opart, const float* __restrict__ Lsum,
                        const float2* __restrict__ cs, const float* __restrict__ gnw,
                        const float* __restrict__ gnb, float* __restrict__ out) {
    int gid = blockIdx.x * 256 + threadIdx.x;    // 262144
    int row = gid >> 9;
    int c8  = (gid & 511) << 3;
    int h   = row >> 6;

    int g = h * 3 + 2;
    int c = threadIdx.x & 63;
    float2 v = cs[g * 64 + c];
    float s = v.x, ss = v.y;
#pragma unroll
    for (int m = 1; m < 64; m <<= 1) { s += __shfl_xor(s, m, 64); ss += __shfl_xor(ss, m, 64); }
    const float N = 262144.0f;
    float mean = s / N;
    float inv  = rsqrtf(ss / N - mean * mean + 1e-5f);
    int gi = h * 192 + 128 + (row & 63);
    float gw = gnw[gi];
    float va = inv * gw;
    float vb = gnb[gi] - mean * inv * gw;

    float o[8] = {0, 0, 0, 0, 0, 0, 0, 0};
    float l[8] = {0, 0, 0, 0, 0, 0, 0, 0};
#pragma unroll
    for (int sp = 0; sp < 4; sp++) {
        bf16x8 vv = *(const bf16x8*)(Opart + sp * 2097152 + row * 4096 + c8);
        const float* L = Lsum + sp * 32768 + h * 4096 + c8;
        float4 l0 = *(const float4*)L;
        float4 l1 = *(const float4*)(L + 4);
#pragma unroll
        for (int j = 0; j < 8; j++) o[j] += (float)vv[j];
        l[0] += l0.x; l[1] += l0.y; l[2] += l0.z; l[3] += l0.w;
        l[4] += l1.x; l[5] += l1.y; l[6] += l1.z; l[7] += l1.w;
    }
    float4 r0, r1;
    r0.x = va * o[0] / l[0] + vb; r0.y = va * o[1] / l[1] + vb;
    r0.z = va * o[2] / l[2] + vb; r0.w = va * o[3] / l[3] + vb;
    r1.x = va * o[4] / l[4] + vb; r1.y = va * o[5] / l[5] + vb;
    r1.z = va * o[6] / l[6] + vb; r1.w = va * o[7] / l[7] + vb;
    *(float4*)(out + row * 4096 + c8)     = r0;
    *(float4*)(out + row * 4096 + c8 + 4) = r1;
}

extern "C" void kernel_launch(void* const* d_in, const int* in_sizes, int n_in,
                              void* d_out, int out_size, void* d_ws, size_t ws_size,
                              hipStream_t stream) {
    const float* x      = (const float*)d_in[0];
    const float* conv_w = (const float*)d_in[1];
    const float* gn_w   = (const float*)d_in[2];
    const float* gn_b   = (const float*)d_in[3];
    float* out = (float*)d_out;
    char* ws = (char*)d_ws;

    // qkvT [0,12582912); Opart 4x4MB [12582912,29360128); Wb/xT alias Opart
    // (dead after k_conv; Opart first written by k_attn).
    bf16*   qkvT  = (bf16*) (ws);
    bf16*   Opart = (bf16*) (ws + 12582912);
    bf16*   Wb    = (bf16*) (ws + 12582912);
    bf16*   xT    = (bf16*) (ws + 13369344);
    float*  Lsum  = (float*)(ws + 29360128);        // 4*131072 B
    float*  cs    = (float*)(ws + 29884416);        // 12288 B

    hipLaunchKernelGGL(k_misc,  dim3(897),  dim3(256), 0, stream, x, conv_w, xT, Wb, cs);
    hipLaunchKernelGGL(k_conv,  dim3(1536), dim3(256), 0, stream, Wb, xT, qkvT, cs);
    hipLaunchKernelGGL(k_attn,  dim3(512),  dim3(256), 0, stream, qkvT, (const float2*)cs, gn_w, gn_b, Opart, Lsum);
    hipLaunchKernelGGL(k_final, dim3(1024), dim3(256), 0, stream, Opart, Lsum, (const float2*)cs, gn_w, gn_b, out);
}

// Round 8
// 165.428 us; speedup vs baseline: 1.0546x; 1.0546x over previous
//
#include <hip/hip_runtime.h>

typedef __bf16 bf16;
typedef __bf16 bf16x8 __attribute__((ext_vector_type(8)));
typedef __bf16 bf16x4 __attribute__((ext_vector_type(4)));
typedef float f32x4 __attribute__((ext_vector_type(4)));
typedef float f32x16 __attribute__((ext_vector_type(16)));

// x: [256][4096] f32, conv_w: [1536][256] f32, out: [512][4096] f32
// heads=8; channels per head: key [0:64), query [64:128), value [128:192)
// qkvT per head (786432): [QT(query) [4096][64] | KT(key) [4096][64] | V [64][4096]]
// k_conv stores RAW bf16; k_normqk normalizes Q (with log2(e)/8) and K in place;
// V affine folds into k_final: out = a_v*(sum O)/(sum L) + b_v.

#define QF 0.18033688011112042f   // log2(e)/8
#define EXPF(x) __builtin_amdgcn_exp2f(x)

union U4 { bf16x4 v; unsigned u[2]; };
union U8 { bf16x8 v; unsigned u[4]; };

// ---------------- K_misc: xpose + cast_w + zero(cs) ----------------
__global__ void k_misc(const float* __restrict__ x, const float* __restrict__ w,
                       bf16* __restrict__ xT, bf16* __restrict__ wb, float* __restrict__ cs) {
    int b = blockIdx.x;
    if (b < 512) {
        int t = b * 256 + threadIdx.x;
        int p  = t & 4095;
        int c0 = (t >> 12) * 8;
        bf16x8 o;
#pragma unroll
        for (int j = 0; j < 8; j++) o[j] = (bf16)x[(c0 + j) * 4096 + p];
        *(bf16x8*)(xT + p * 256 + c0) = o;
    } else if (b < 896) {
        int idx = ((b - 512) * 256 + threadIdx.x) * 4;
        float4 f = *(const float4*)(w + idx);
        bf16x4 o;
        o[0] = (bf16)f.x; o[1] = (bf16)f.y; o[2] = (bf16)f.z; o[3] = (bf16)f.w;
        *(bf16x4*)(wb + idx) = o;
    } else {
#pragma unroll
        for (int i = 0; i < 12; i++) cs[i * 256 + threadIdx.x] = 0.f;
    }
}

// ---------------- K1: conv GEMM -> stats + LDS-transposed coalesced stores ----------------
__global__ __launch_bounds__(256) void k_conv(const bf16* __restrict__ Wb,
                                              const bf16* __restrict__ xT,
                                              bf16* __restrict__ qkvT,
                                              float* __restrict__ cs) {
    __shared__ __attribute__((aligned(16))) bf16 tile[64 * 72];
    int wid = threadIdx.x >> 6, lane = threadIdx.x & 63;
    int quad = lane >> 4, l15 = lane & 15;
    int g  = blockIdx.x % 24;
    int pb = (blockIdx.x / 24) * 64;
    int h = g / 3, sec = g % 3;          // 0=key 1=query 2=value
    int ob = g * 64;
    int orow = ob + wid * 16 + l15;

    f32x4 acc[4];
#pragma unroll
    for (int c = 0; c < 4; c++) acc[c] = (f32x4){0.f, 0.f, 0.f, 0.f};

#pragma unroll
    for (int ks = 0; ks < 8; ks++) {
        bf16x8 a = *(const bf16x8*)(Wb + orow * 256 + ks * 32 + quad * 8);
#pragma unroll
        for (int c = 0; c < 4; c++) {
            bf16x8 b = *(const bf16x8*)(xT + (pb + c * 16 + l15) * 256 + ks * 32 + quad * 8);
            acc[c] = __builtin_amdgcn_mfma_f32_16x16x32_bf16(a, b, acc[c], 0, 0, 0);
        }
    }

    int ch0 = wid * 16 + quad * 4;
#pragma unroll
    for (int r = 0; r < 4; r++) {
        float sp  = acc[0][r] + acc[1][r] + acc[2][r] + acc[3][r];
        float ssp = acc[0][r] * acc[0][r] + acc[1][r] * acc[1][r]
                  + acc[2][r] * acc[2][r] + acc[3][r] * acc[3][r];
#pragma unroll
        for (int m = 1; m < 16; m <<= 1) {
            sp  += __shfl_xor(sp,  m, 64);
            ssp += __shfl_xor(ssp, m, 64);
        }
        if (l15 == 0) {
            atomicAdd(cs + (ob + ch0 + r) * 2,     sp);
            atomicAdd(cs + (ob + ch0 + r) * 2 + 1, ssp);
        }
    }

    if (sec == 2) {                      // V wants [ch][px]
#pragma unroll
        for (int c = 0; c < 4; c++)
#pragma unroll
            for (int r = 0; r < 4; r++)
                tile[(ch0 + r) * 72 + c * 16 + l15] = (bf16)acc[c][r];
    } else {                             // Q/K want [px][ch]
#pragma unroll
        for (int c = 0; c < 4; c++) {
            bf16x4 o;
#pragma unroll
            for (int r = 0; r < 4; r++) o[r] = (bf16)acc[c][r];
            *(bf16x4*)(&tile[(c * 16 + l15) * 72 + ch0]) = o;
        }
    }
    __syncthreads();
    bf16* base = qkvT + h * 786432;
    int t = threadIdx.x;
    if (sec == 2) {
        bf16* V = base + 524288;
#pragma unroll
        for (int it = 0; it < 2; it++) {
            int e = it * 256 + t; int ch = e >> 3; int pxo = (e & 7) * 8;
            *(bf16x8*)(V + ch * 4096 + pb + pxo) = *(const bf16x8*)(&tile[ch * 72 + pxo]);
        }
    } else {
        bf16* dst = base + (sec == 0 ? 262144 : 0);
#pragma unroll
        for (int it = 0; it < 2; it++) {
            int e = it * 256 + t; int px = e >> 3; int cho = (e & 7) * 8;
            *(bf16x8*)(dst + (pb + px) * 64 + cho) = *(const bf16x8*)(&tile[px * 72 + cho]);
        }
    }
}

// ---------------- K2: in-place affine on Q/K (group stats inline) ----------------
__global__ __launch_bounds__(256) void k_normqk(bf16* __restrict__ qkv,
                                                const float2* __restrict__ cs,
                                                const float* __restrict__ gnw,
                                                const float* __restrict__ gnb) {
    int h    = blockIdx.x >> 8;
    int base = (blockIdx.x & 255) * 2048;            // section-pure (128 WGs per section)
    int isQ  = base < 262144;
    int g    = h * 3 + (isQ ? 1 : 0);

    int c = threadIdx.x & 63;
    float2 v = cs[g * 64 + c];
    float s = v.x, ss = v.y;
#pragma unroll
    for (int m = 1; m < 64; m <<= 1) { s += __shfl_xor(s, m, 64); ss += __shfl_xor(ss, m, 64); }
    const float N = 262144.0f;
    float mean = s / N;
    float inv  = rsqrtf(ss / N - mean * mean + 1e-5f);
    float f = isQ ? QF : 1.0f;

    int e = base + threadIdx.x * 8;
    int gc = h * 192 + (isQ ? 64 : 0) + (e & 63);
    bf16* p = qkv + h * 786432 + e;
    bf16x8 vv = *(bf16x8*)p;
    bf16x8 o;
#pragma unroll
    for (int j = 0; j < 8; j++) {
        float gw = gnw[gc + j];
        float a = inv * gw * f;
        float b = (gnb[gc + j] - mean * inv * gw) * f;
        o[j] = (bf16)(a * (float)vv[j] + b);
    }
    *(bf16x8*)p = o;
}

// helper macro: one 32x32 C-block (S) -> exp2 -> two PV B-fragments (spill-free)
#define PF_BLOCK(S, PFA, PFB)                                                   \
    {                                                                           \
        float p0 = EXPF(S[0]),  p1 = EXPF(S[1]),  p2 = EXPF(S[2]),  p3 = EXPF(S[3]);   \
        float p4 = EXPF(S[4]),  p5 = EXPF(S[5]),  p6 = EXPF(S[6]),  p7 = EXPF(S[7]);   \
        float p8 = EXPF(S[8]),  p9 = EXPF(S[9]),  p10 = EXPF(S[10]), p11 = EXPF(S[11]); \
        float p12 = EXPF(S[12]), p13 = EXPF(S[13]), p14 = EXPF(S[14]), p15 = EXPF(S[15]); \
        lacc += (((p0 + p1) + (p2 + p3)) + ((p4 + p5) + (p6 + p7)))             \
              + (((p8 + p9) + (p10 + p11)) + ((p12 + p13) + (p14 + p15)));      \
        U4 lo, hi;                                                              \
        lo.v[0] = (bf16)p0;  lo.v[1] = (bf16)p1;  lo.v[2] = (bf16)p2;  lo.v[3] = (bf16)p3;  \
        hi.v[0] = (bf16)p4;  hi.v[1] = (bf16)p5;  hi.v[2] = (bf16)p6;  hi.v[3] = (bf16)p7;  \
        unsigned sa = half ? lo.u[0] : hi.u[0];                                 \
        unsigned sb = half ? lo.u[1] : hi.u[1];                                 \
        unsigned ra = (unsigned)__shfl_xor((int)sa, 32, 64);                    \
        unsigned rb = (unsigned)__shfl_xor((int)sb, 32, 64);                    \
        U8 fA;                                                                  \
        fA.u[0] = half ? ra : lo.u[0];  fA.u[1] = half ? rb : lo.u[1];          \
        fA.u[2] = half ? hi.u[0] : ra;  fA.u[3] = half ? hi.u[1] : rb;          \
        PFA = fA.v;                                                             \
        U4 lo2, hi2;                                                            \
        lo2.v[0] = (bf16)p8;  lo2.v[1] = (bf16)p9;  lo2.v[2] = (bf16)p10; lo2.v[3] = (bf16)p11; \
        hi2.v[0] = (bf16)p12; hi2.v[1] = (bf16)p13; hi2.v[2] = (bf16)p14; hi2.v[3] = (bf16)p15; \
        unsigned sc = half ? lo2.u[0] : hi2.u[0];                               \
        unsigned sd = half ? lo2.u[1] : hi2.u[1];                               \
        unsigned rc = (unsigned)__shfl_xor((int)sc, 32, 64);                    \
        unsigned rd = (unsigned)__shfl_xor((int)sd, 32, 64);                    \
        U8 fB;                                                                  \
        fB.u[0] = half ? rc : lo2.u[0];  fB.u[1] = half ? rd : lo2.u[1];        \
        fB.u[2] = half ? hi2.u[0] : rc;  fB.u[3] = half ? hi2.u[1] : rd;        \
        PFB = fB.v;                                                             \
    }

// ---------------- K3: flash attention, 32x32x16, P via half-wave exchange ----------------
// grid 512 = 8 heads x 16 q-blocks(256q) x 4 L-splits; wave owns 64 q.
__global__ __launch_bounds__(256, 2) void k_attn(const bf16* __restrict__ qkvT,
                                                 bf16* __restrict__ Opart,
                                                 float* __restrict__ Lsum) {
    int bid   = blockIdx.x;
    int h     = bid & 7;                  // XCD L2 affinity
    int qb    = (bid >> 3) & 15;
    int split = bid >> 7;                 // 0..3
    int wid = threadIdx.x >> 6, lane = threadIdx.x & 63;
    int l31 = lane & 31, half = lane >> 5;
    const bf16* QT = qkvT + h * 786432;
    const bf16* KT = QT + 262144;
    const bf16* V  = QT + 524288;
    int qw = qb * 256 + wid * 64;

    __shared__ __attribute__((aligned(16))) bf16 Ks[64 * 72];
    __shared__ __attribute__((aligned(16))) bf16 Vs[64 * 72];

    int r0   = threadIdx.x >> 3;          // staging rows r0 and r0+32
    int koff = (threadIdx.x & 7) * 8;

    // Q B-fragments (normalized already): B[n=q][k=kd]
    bf16x8 bq[2][4];
#pragma unroll
    for (int ks = 0; ks < 4; ks++)
#pragma unroll
        for (int qs = 0; qs < 2; qs++)
            bq[qs][ks] = *(const bf16x8*)(QT + (qw + qs * 32 + l31) * 64 + ks * 16 + half * 8);

    f32x16 oacc[2][2];                    // [kd-block][qs]
#pragma unroll
    for (int kb = 0; kb < 2; kb++)
#pragma unroll
        for (int qs = 0; qs < 2; qs++) oacc[kb][qs] = (f32x16)(0.0f);
    float ls0 = 0.f, ls1 = 0.f;

    int t0 = split * 16, t1 = t0 + 16;

    bf16x8 kf0, kf1, vf0, vf1;            // register prefetch
    {
        int lb0 = t0 * 64;
        kf0 = *(const bf16x8*)(KT + (lb0 + r0) * 64 + koff);
        kf1 = *(const bf16x8*)(KT + (lb0 + r0 + 32) * 64 + koff);
        vf0 = *(const bf16x8*)(V + r0 * 4096 + lb0 + koff);
        vf1 = *(const bf16x8*)(V + (r0 + 32) * 4096 + lb0 + koff);
    }

    for (int lt = t0; lt < t1; lt++) {
        __syncthreads();
        *(bf16x8*)(Ks + r0 * 72 + koff)        = kf0;
        *(bf16x8*)(Ks + (r0 + 32) * 72 + koff) = kf1;
        *(bf16x8*)(Vs + r0 * 72 + koff)        = vf0;
        *(bf16x8*)(Vs + (r0 + 32) * 72 + koff) = vf1;
        __syncthreads();

        if (lt + 1 < t1) {
            int nb = (lt + 1) * 64;
            kf0 = *(const bf16x8*)(KT + (nb + r0) * 64 + koff);
            kf1 = *(const bf16x8*)(KT + (nb + r0 + 32) * 64 + koff);
            vf0 = *(const bf16x8*)(V + r0 * 4096 + nb + koff);
            vf1 = *(const bf16x8*)(V + (r0 + 32) * 4096 + nb + koff);
        }

        // K A-frags: A[m=l][k=kd], loaded once, reused by both qs
        bf16x8 ak00 = *(const bf16x8*)(Ks + (l31) * 72 +  0 + half * 8);
        bf16x8 ak01 = *(const bf16x8*)(Ks + (l31) * 72 + 16 + half * 8);
        bf16x8 ak02 = *(const bf16x8*)(Ks + (l31) * 72 + 32 + half * 8);
        bf16x8 ak03 = *(const bf16x8*)(Ks + (l31) * 72 + 48 + half * 8);
        bf16x8 ak10 = *(const bf16x8*)(Ks + (32 + l31) * 72 +  0 + half * 8);
        bf16x8 ak11 = *(const bf16x8*)(Ks + (32 + l31) * 72 + 16 + half * 8);
        bf16x8 ak12 = *(const bf16x8*)(Ks + (32 + l31) * 72 + 32 + half * 8);
        bf16x8 ak13 = *(const bf16x8*)(Ks + (32 + l31) * 72 + 48 + half * 8);

#pragma unroll
        for (int qs = 0; qs < 2; qs++) {
            // S^T = K·Q : two 32x32 C-tiles, col q = lane&31
            f32x16 s0 = (f32x16)(0.0f), s1 = (f32x16)(0.0f);
            s0 = __builtin_amdgcn_mfma_f32_32x32x16_bf16(ak00, bq[qs][0], s0, 0, 0, 0);
            s1 = __builtin_amdgcn_mfma_f32_32x32x16_bf16(ak10, bq[qs][0], s1, 0, 0, 0);
            s0 = __builtin_amdgcn_mfma_f32_32x32x16_bf16(ak01, bq[qs][1], s0, 0, 0, 0);
            s1 = __builtin_amdgcn_mfma_f32_32x32x16_bf16(ak11, bq[qs][1], s1, 0, 0, 0);
            s0 = __builtin_amdgcn_mfma_f32_32x32x16_bf16(ak02, bq[qs][2], s0, 0, 0, 0);
            s1 = __builtin_amdgcn_mfma_f32_32x32x16_bf16(ak12, bq[qs][2], s1, 0, 0, 0);
            s0 = __builtin_amdgcn_mfma_f32_32x32x16_bf16(ak03, bq[qs][3], s0, 0, 0, 0);
            s1 = __builtin_amdgcn_mfma_f32_32x32x16_bf16(ak13, bq[qs][3], s1, 0, 0, 0);

            float lacc = (qs == 0) ? ls0 : ls1;
            bf16x8 pf0, pf1, pf2, pf3;
            PF_BLOCK(s0, pf0, pf1);       // l 0..31
            PF_BLOCK(s1, pf2, pf3);       // l 32..63
            if (qs == 0) ls0 = lacc; else ls1 = lacc;

            // O[kd][q] += V·P ; V A-frags read per use (saves registers)
            oacc[0][qs] = __builtin_amdgcn_mfma_f32_32x32x16_bf16(
                *(const bf16x8*)(Vs + l31 * 72 +  0 + half * 8), pf0, oacc[0][qs], 0, 0, 0);
            oacc[1][qs] = __builtin_amdgcn_mfma_f32_32x32x16_bf16(
                *(const bf16x8*)(Vs + (32 + l31) * 72 +  0 + half * 8), pf0, oacc[1][qs], 0, 0, 0);
            oacc[0][qs] = __builtin_amdgcn_mfma_f32_32x32x16_bf16(
                *(const bf16x8*)(Vs + l31 * 72 + 16 + half * 8), pf1, oacc[0][qs], 0, 0, 0);
            oacc[1][qs] = __builtin_amdgcn_mfma_f32_32x32x16_bf16(
                *(const bf16x8*)(Vs + (32 + l31) * 72 + 16 + half * 8), pf1, oacc[1][qs], 0, 0, 0);
            oacc[0][qs] = __builtin_amdgcn_mfma_f32_32x32x16_bf16(
                *(const bf16x8*)(Vs + l31 * 72 + 32 + half * 8), pf2, oacc[0][qs], 0, 0, 0);
            oacc[1][qs] = __builtin_amdgcn_mfma_f32_32x32x16_bf16(
                *(const bf16x8*)(Vs + (32 + l31) * 72 + 32 + half * 8), pf2, oacc[1][qs], 0, 0, 0);
            oacc[0][qs] = __builtin_amdgcn_mfma_f32_32x32x16_bf16(
                *(const bf16x8*)(Vs + l31 * 72 + 48 + half * 8), pf3, oacc[0][qs], 0, 0, 0);
            oacc[1][qs] = __builtin_amdgcn_mfma_f32_32x32x16_bf16(
                *(const bf16x8*)(Vs + (32 + l31) * 72 + 48 + half * 8), pf3, oacc[1][qs], 0, 0, 0);
        }
    }

    // denominators: halves hold complementary l-rows of col q
    ls0 += __shfl_xor(ls0, 32, 64);
    ls1 += __shfl_xor(ls1, 32, 64);
    if (half == 0) {
        Lsum[split * 32768 + h * 4096 + qw + l31]      = ls0;
        Lsum[split * 32768 + h * 4096 + qw + 32 + l31] = ls1;
    }

    // partial O (unnormalized, bf16): row = h*64+kd, col = q
    bf16* Ob = Opart + split * 2097152;
#pragma unroll
    for (int kb = 0; kb < 2; kb++)
#pragma unroll
        for (int qs = 0; qs < 2; qs++)
#pragma unroll
            for (int r = 0; r < 16; r++) {
                int kd = kb * 32 + (r & 3) + 8 * (r >> 2) + 4 * half;
                Ob[(h * 64 + kd) * 4096 + qw + qs * 32 + l31] = (bf16)oacc[kb][qs][r];
            }
}

// ---------------- K4: combine 4 splits + V affine (stats inline) + normalize ----------------
__global__ void k_final(const bf16* __restrict__ Opart, const float* __restrict__ Lsum,
                        const float2* __restrict__ cs, const float* __restrict__ gnw,
                        const float* __restrict__ gnb, float* __restrict__ out) {
    int gid = blockIdx.x * 256 + threadIdx.x;    // 262144
    int row = gid >> 9;
    int c8  = (gid & 511) << 3;
    int h   = row >> 6;

    int g = h * 3 + 2;
    int c = threadIdx.x & 63;
    float2 v = cs[g * 64 + c];
    float s = v.x, ss = v.y;
#pragma unroll
    for (int m = 1; m < 64; m <<= 1) { s += __shfl_xor(s, m, 64); ss += __shfl_xor(ss, m, 64); }
    const float N = 262144.0f;
    float mean = s / N;
    float inv  = rsqrtf(ss / N - mean * mean + 1e-5f);
    int gi = h * 192 + 128 + (row & 63);
    float gw = gnw[gi];
    float va = inv * gw;
    float vb = gnb[gi] - mean * inv * gw;

    float o[8] = {0, 0, 0, 0, 0, 0, 0, 0};
    float l[8] = {0, 0, 0, 0, 0, 0, 0, 0};
#pragma unroll
    for (int sp = 0; sp < 4; sp++) {
        bf16x8 vv = *(const bf16x8*)(Opart + sp * 2097152 + row * 4096 + c8);
        const float* L = Lsum + sp * 32768 + h * 4096 + c8;
        float4 l0 = *(const float4*)L;
        float4 l1 = *(const float4*)(L + 4);
#pragma unroll
        for (int j = 0; j < 8; j++) o[j] += (float)vv[j];
        l[0] += l0.x; l[1] += l0.y; l[2] += l0.z; l[3] += l0.w;
        l[4] += l1.x; l[5] += l1.y; l[6] += l1.z; l[7] += l1.w;
    }
    float4 r0, r1;
    r0.x = va * o[0] / l[0] + vb; r0.y = va * o[1] / l[1] + vb;
    r0.z = va * o[2] / l[2] + vb; r0.w = va * o[3] / l[3] + vb;
    r1.x = va * o[4] / l[4] + vb; r1.y = va * o[5] / l[5] + vb;
    r1.z = va * o[6] / l[6] + vb; r1.w = va * o[7] / l[7] + vb;
    *(float4*)(out + row * 4096 + c8)     = r0;
    *(float4*)(out + row * 4096 + c8 + 4) = r1;
}

extern "C" void kernel_launch(void* const* d_in, const int* in_sizes, int n_in,
                              void* d_out, int out_size, void* d_ws, size_t ws_size,
                              hipStream_t stream) {
    const float* x      = (const float*)d_in[0];
    const float* conv_w = (const float*)d_in[1];
    const float* gn_w   = (const float*)d_in[2];
    const float* gn_b   = (const float*)d_in[3];
    float* out = (float*)d_out;
    char* ws = (char*)d_ws;

    // qkvT [0,12582912); Opart 4x4MB [12582912,29360128); Wb/xT alias Opart
    // (dead after k_conv; Opart first written by k_attn).
    bf16*   qkvT  = (bf16*) (ws);
    bf16*   Opart = (bf16*) (ws + 12582912);
    bf16*   Wb    = (bf16*) (ws + 12582912);
    bf16*   xT    = (bf16*) (ws + 13369344);
    float*  Lsum  = (float*)(ws + 29360128);        // 4*131072 B
    float*  cs    = (float*)(ws + 29884416);        // 12288 B

    hipLaunchKernelGGL(k_misc,   dim3(897),  dim3(256), 0, stream, x, conv_w, xT, Wb, cs);
    hipLaunchKernelGGL(k_conv,   dim3(1536), dim3(256), 0, stream, Wb, xT, qkvT, cs);
    hipLaunchKernelGGL(k_normqk, dim3(2048), dim3(256), 0, stream, qkvT, (const float2*)cs, gn_w, gn_b);
    hipLaunchKernelGGL(k_attn,   dim3(512),  dim3(256), 0, stream, qkvT, Opart, Lsum);
    hipLaunchKernelGGL(k_final,  dim3(1024), dim3(256), 0, stream, Opart, Lsum, (const float2*)cs, gn_w, gn_b, out);
}

// Round 9
// 155.482 us; speedup vs baseline: 1.1221x; 1.0640x over previous
//
#include <hip/hip_runtime.h>

typedef __bf16 bf16;
typedef __bf16 bf16x8 __attribute__((ext_vector_type(8)));
typedef __bf16 bf16x4 __attribute__((ext_vector_type(4)));
typedef float f32x4 __attribute__((ext_vector_type(4)));
typedef float f32x16 __attribute__((ext_vector_type(16)));

// x: [256][4096] f32, conv_w: [1536][256] f32, out: [512][4096] f32
// heads=8; channels per head: key [0:64), query [64:128), value [128:192)
// qkvT per head (786432): [QT(query) [4096][64] | KT(key) [4096][64] | V [64][4096]]
// k_conv stores RAW bf16; k_normqk normalizes Q (with log2(e)/8) and K in place;
// V affine folds into k_final: out = a_v*(sum O)/(sum L) + b_v.

#define QF 0.18033688011112042f   // log2(e)/8
#define EXPF(x) __builtin_amdgcn_exp2f(x)

union U4 { bf16x4 v; unsigned u[2]; };
union U8 { bf16x8 v; unsigned u[4]; };

// ---------------- K_misc: xpose + cast_w + zero(cs) ----------------
__global__ void k_misc(const float* __restrict__ x, const float* __restrict__ w,
                       bf16* __restrict__ xT, bf16* __restrict__ wb, float* __restrict__ cs) {
    int b = blockIdx.x;
    if (b < 512) {
        int t = b * 256 + threadIdx.x;
        int p  = t & 4095;
        int c0 = (t >> 12) * 8;
        bf16x8 o;
#pragma unroll
        for (int j = 0; j < 8; j++) o[j] = (bf16)x[(c0 + j) * 4096 + p];
        *(bf16x8*)(xT + p * 256 + c0) = o;
    } else if (b < 896) {
        int idx = ((b - 512) * 256 + threadIdx.x) * 4;
        float4 f = *(const float4*)(w + idx);
        bf16x4 o;
        o[0] = (bf16)f.x; o[1] = (bf16)f.y; o[2] = (bf16)f.z; o[3] = (bf16)f.w;
        *(bf16x4*)(wb + idx) = o;
    } else {
#pragma unroll
        for (int i = 0; i < 12; i++) cs[i * 256 + threadIdx.x] = 0.f;
    }
}

// ---------------- K1: conv GEMM -> stats + LDS-transposed coalesced stores ----------------
__global__ __launch_bounds__(256) void k_conv(const bf16* __restrict__ Wb,
                                              const bf16* __restrict__ xT,
                                              bf16* __restrict__ qkvT,
                                              float* __restrict__ cs) {
    __shared__ __attribute__((aligned(16))) bf16 tile[64 * 72];
    int wid = threadIdx.x >> 6, lane = threadIdx.x & 63;
    int quad = lane >> 4, l15 = lane & 15;
    int g  = blockIdx.x % 24;
    int pb = (blockIdx.x / 24) * 64;
    int h = g / 3, sec = g % 3;          // 0=key 1=query 2=value
    int ob = g * 64;
    int orow = ob + wid * 16 + l15;

    f32x4 acc[4];
#pragma unroll
    for (int c = 0; c < 4; c++) acc[c] = (f32x4){0.f, 0.f, 0.f, 0.f};

#pragma unroll
    for (int ks = 0; ks < 8; ks++) {
        bf16x8 a = *(const bf16x8*)(Wb + orow * 256 + ks * 32 + quad * 8);
#pragma unroll
        for (int c = 0; c < 4; c++) {
            bf16x8 b = *(const bf16x8*)(xT + (pb + c * 16 + l15) * 256 + ks * 32 + quad * 8);
            acc[c] = __builtin_amdgcn_mfma_f32_16x16x32_bf16(a, b, acc[c], 0, 0, 0);
        }
    }

    int ch0 = wid * 16 + quad * 4;
#pragma unroll
    for (int r = 0; r < 4; r++) {
        float sp  = acc[0][r] + acc[1][r] + acc[2][r] + acc[3][r];
        float ssp = acc[0][r] * acc[0][r] + acc[1][r] * acc[1][r]
                  + acc[2][r] * acc[2][r] + acc[3][r] * acc[3][r];
#pragma unroll
        for (int m = 1; m < 16; m <<= 1) {
            sp  += __shfl_xor(sp,  m, 64);
            ssp += __shfl_xor(ssp, m, 64);
        }
        if (l15 == 0) {
            atomicAdd(cs + (ob + ch0 + r) * 2,     sp);
            atomicAdd(cs + (ob + ch0 + r) * 2 + 1, ssp);
        }
    }

    if (sec == 2) {                      // V wants [ch][px]
#pragma unroll
        for (int c = 0; c < 4; c++)
#pragma unroll
            for (int r = 0; r < 4; r++)
                tile[(ch0 + r) * 72 + c * 16 + l15] = (bf16)acc[c][r];
    } else {                             // Q/K want [px][ch]
#pragma unroll
        for (int c = 0; c < 4; c++) {
            bf16x4 o;
#pragma unroll
            for (int r = 0; r < 4; r++) o[r] = (bf16)acc[c][r];
            *(bf16x4*)(&tile[(c * 16 + l15) * 72 + ch0]) = o;
        }
    }
    __syncthreads();
    bf16* base = qkvT + h * 786432;
    int t = threadIdx.x;
    if (sec == 2) {
        bf16* V = base + 524288;
#pragma unroll
        for (int it = 0; it < 2; it++) {
            int e = it * 256 + t; int ch = e >> 3; int pxo = (e & 7) * 8;
            *(bf16x8*)(V + ch * 4096 + pb + pxo) = *(const bf16x8*)(&tile[ch * 72 + pxo]);
        }
    } else {
        bf16* dst = base + (sec == 0 ? 262144 : 0);
#pragma unroll
        for (int it = 0; it < 2; it++) {
            int e = it * 256 + t; int px = e >> 3; int cho = (e & 7) * 8;
            *(bf16x8*)(dst + (pb + px) * 64 + cho) = *(const bf16x8*)(&tile[px * 72 + cho]);
        }
    }
}

// ---------------- K2: in-place affine on Q/K (group stats inline) ----------------
__global__ __launch_bounds__(256) void k_normqk(bf16* __restrict__ qkv,
                                                const float2* __restrict__ cs,
                                                const float* __restrict__ gnw,
                                                const float* __restrict__ gnb) {
    int h    = blockIdx.x >> 8;
    int base = (blockIdx.x & 255) * 2048;            // section-pure (128 WGs per section)
    int isQ  = base < 262144;
    int g    = h * 3 + (isQ ? 1 : 0);

    int c = threadIdx.x & 63;
    float2 v = cs[g * 64 + c];
    float s = v.x, ss = v.y;
#pragma unroll
    for (int m = 1; m < 64; m <<= 1) { s += __shfl_xor(s, m, 64); ss += __shfl_xor(ss, m, 64); }
    const float N = 262144.0f;
    float mean = s / N;
    float inv  = rsqrtf(ss / N - mean * mean + 1e-5f);
    float f = isQ ? QF : 1.0f;

    int e = base + threadIdx.x * 8;
    int gc = h * 192 + (isQ ? 64 : 0) + (e & 63);
    bf16* p = qkv + h * 786432 + e;
    bf16x8 vv = *(bf16x8*)p;
    bf16x8 o;
#pragma unroll
    for (int j = 0; j < 8; j++) {
        float gw = gnw[gc + j];
        float a = inv * gw * f;
        float b = (gnb[gc + j] - mean * inv * gw) * f;
        o[j] = (bf16)(a * (float)vv[j] + b);
    }
    *(bf16x8*)p = o;
}

// helper: one 32x32 C-block (S) -> exp2 -> two PV B-fragments (named scalars only)
#define PF_BLOCK(S, PFA, PFB)                                                   \
    {                                                                           \
        float p0 = EXPF(S[0]),  p1 = EXPF(S[1]),  p2 = EXPF(S[2]),  p3 = EXPF(S[3]);   \
        float p4 = EXPF(S[4]),  p5 = EXPF(S[5]),  p6 = EXPF(S[6]),  p7 = EXPF(S[7]);   \
        float p8 = EXPF(S[8]),  p9 = EXPF(S[9]),  p10 = EXPF(S[10]), p11 = EXPF(S[11]); \
        float p12 = EXPF(S[12]), p13 = EXPF(S[13]), p14 = EXPF(S[14]), p15 = EXPF(S[15]); \
        lacc += (((p0 + p1) + (p2 + p3)) + ((p4 + p5) + (p6 + p7)))             \
              + (((p8 + p9) + (p10 + p11)) + ((p12 + p13) + (p14 + p15)));      \
        U4 lo, hi;                                                              \
        lo.v[0] = (bf16)p0;  lo.v[1] = (bf16)p1;  lo.v[2] = (bf16)p2;  lo.v[3] = (bf16)p3;  \
        hi.v[0] = (bf16)p4;  hi.v[1] = (bf16)p5;  hi.v[2] = (bf16)p6;  hi.v[3] = (bf16)p7;  \
        unsigned sa = half ? lo.u[0] : hi.u[0];                                 \
        unsigned sb = half ? lo.u[1] : hi.u[1];                                 \
        unsigned ra = (unsigned)__shfl_xor((int)sa, 32, 64);                    \
        unsigned rb = (unsigned)__shfl_xor((int)sb, 32, 64);                    \
        U8 fA;                                                                  \
        fA.u[0] = half ? ra : lo.u[0];  fA.u[1] = half ? rb : lo.u[1];          \
        fA.u[2] = half ? hi.u[0] : ra;  fA.u[3] = half ? hi.u[1] : rb;          \
        PFA = fA.v;                                                             \
        U4 lo2, hi2;                                                            \
        lo2.v[0] = (bf16)p8;  lo2.v[1] = (bf16)p9;  lo2.v[2] = (bf16)p10; lo2.v[3] = (bf16)p11; \
        hi2.v[0] = (bf16)p12; hi2.v[1] = (bf16)p13; hi2.v[2] = (bf16)p14; hi2.v[3] = (bf16)p15; \
        unsigned sc = half ? lo2.u[0] : hi2.u[0];                               \
        unsigned sd = half ? lo2.u[1] : hi2.u[1];                               \
        unsigned rc = (unsigned)__shfl_xor((int)sc, 32, 64);                    \
        unsigned rd = (unsigned)__shfl_xor((int)sd, 32, 64);                    \
        U8 fB;                                                                  \
        fB.u[0] = half ? rc : lo2.u[0];  fB.u[1] = half ? rd : lo2.u[1];        \
        fB.u[2] = half ? hi2.u[0] : rc;  fB.u[3] = half ? hi2.u[1] : rd;        \
        PFB = fB.v;                                                             \
    }

// ---------------- K3: flash attention, 32x32x16, 32q/wave, 3 waves/SIMD ----------------
// grid 768 = 8 heads x 32 q-blocks(128q) x 3 L-splits; wave owns 32 q.
__global__ __launch_bounds__(256, 3) void k_attn(const bf16* __restrict__ qkvT,
                                                 bf16* __restrict__ Opart,
                                                 float* __restrict__ Lsum) {
    int bid   = blockIdx.x;
    int h     = bid & 7;                  // XCD L2 affinity
    int qb    = (bid >> 3) & 31;
    int split = bid >> 8;                 // 0..2
    int wid = threadIdx.x >> 6, lane = threadIdx.x & 63;
    int l31 = lane & 31, half = lane >> 5;
    const bf16* QT = qkvT + h * 786432;
    const bf16* KT = QT + 262144;
    const bf16* V  = QT + 524288;
    int qw = qb * 128 + wid * 32;         // wave's 32 q

    __shared__ __attribute__((aligned(16))) bf16 Ks[64 * 72];
    __shared__ __attribute__((aligned(16))) bf16 Vs[64 * 72];

    int r0   = threadIdx.x >> 3;          // staging rows r0 and r0+32
    int koff = (threadIdx.x & 7) * 8;

    // Q B-fragments (normalized already): B[n=q][k=kd]
    bf16x8 bq[4];
#pragma unroll
    for (int ks = 0; ks < 4; ks++)
        bq[ks] = *(const bf16x8*)(QT + (qw + l31) * 64 + ks * 16 + half * 8);

    f32x16 oacc0 = (f32x16)(0.0f), oacc1 = (f32x16)(0.0f);   // kd 0-31, 32-63
    float ls = 0.f;

    int t0 = (split * 64) / 3, t1 = ((split + 1) * 64) / 3;

    bf16x8 kf0, kf1, vf0, vf1;            // register prefetch
    {
        int lb0 = t0 * 64;
        kf0 = *(const bf16x8*)(KT + (lb0 + r0) * 64 + koff);
        kf1 = *(const bf16x8*)(KT + (lb0 + r0 + 32) * 64 + koff);
        vf0 = *(const bf16x8*)(V + r0 * 4096 + lb0 + koff);
        vf1 = *(const bf16x8*)(V + (r0 + 32) * 4096 + lb0 + koff);
    }

    for (int lt = t0; lt < t1; lt++) {
        __syncthreads();
        *(bf16x8*)(Ks + r0 * 72 + koff)        = kf0;
        *(bf16x8*)(Ks + (r0 + 32) * 72 + koff) = kf1;
        *(bf16x8*)(Vs + r0 * 72 + koff)        = vf0;
        *(bf16x8*)(Vs + (r0 + 32) * 72 + koff) = vf1;
        __syncthreads();

        if (lt + 1 < t1) {
            int nb = (lt + 1) * 64;
            kf0 = *(const bf16x8*)(KT + (nb + r0) * 64 + koff);
            kf1 = *(const bf16x8*)(KT + (nb + r0 + 32) * 64 + koff);
            vf0 = *(const bf16x8*)(V + r0 * 4096 + nb + koff);
            vf1 = *(const bf16x8*)(V + (r0 + 32) * 4096 + nb + koff);
        }

        // S^T = K·Q : two 32x32 C-tiles (l 0-31, 32-63), col q = lane&31
        // K A-frags read per-use from LDS (keeps arch VGPR pressure low)
        f32x16 s0 = (f32x16)(0.0f), s1 = (f32x16)(0.0f);
#pragma unroll
        for (int ks = 0; ks < 4; ks++) {
            s0 = __builtin_amdgcn_mfma_f32_32x32x16_bf16(
                *(const bf16x8*)(Ks + l31 * 72 + ks * 16 + half * 8), bq[ks], s0, 0, 0, 0);
            s1 = __builtin_amdgcn_mfma_f32_32x32x16_bf16(
                *(const bf16x8*)(Ks + (32 + l31) * 72 + ks * 16 + half * 8), bq[ks], s1, 0, 0, 0);
        }

        float lacc = ls;
        bf16x8 pf0, pf1, pf2, pf3;
        PF_BLOCK(s0, pf0, pf1);           // l 0..31
        PF_BLOCK(s1, pf2, pf3);           // l 32..63
        ls = lacc;

        // O[kd][q] += V·P ; V A-frags read per-use from LDS
        oacc0 = __builtin_amdgcn_mfma_f32_32x32x16_bf16(
            *(const bf16x8*)(Vs + l31 * 72 +  0 + half * 8), pf0, oacc0, 0, 0, 0);
        oacc1 = __builtin_amdgcn_mfma_f32_32x32x16_bf16(
            *(const bf16x8*)(Vs + (32 + l31) * 72 +  0 + half * 8), pf0, oacc1, 0, 0, 0);
        oacc0 = __builtin_amdgcn_mfma_f32_32x32x16_bf16(
            *(const bf16x8*)(Vs + l31 * 72 + 16 + half * 8), pf1, oacc0, 0, 0, 0);
        oacc1 = __builtin_amdgcn_mfma_f32_32x32x16_bf16(
            *(const bf16x8*)(Vs + (32 + l31) * 72 + 16 + half * 8), pf1, oacc1, 0, 0, 0);
        oacc0 = __builtin_amdgcn_mfma_f32_32x32x16_bf16(
            *(const bf16x8*)(Vs + l31 * 72 + 32 + half * 8), pf2, oacc0, 0, 0, 0);
        oacc1 = __builtin_amdgcn_mfma_f32_32x32x16_bf16(
            *(const bf16x8*)(Vs + (32 + l31) * 72 + 32 + half * 8), pf2, oacc1, 0, 0, 0);
        oacc0 = __builtin_amdgcn_mfma_f32_32x32x16_bf16(
            *(const bf16x8*)(Vs + l31 * 72 + 48 + half * 8), pf3, oacc0, 0, 0, 0);
        oacc1 = __builtin_amdgcn_mfma_f32_32x32x16_bf16(
            *(const bf16x8*)(Vs + (32 + l31) * 72 + 48 + half * 8), pf3, oacc1, 0, 0, 0);
    }

    // denominator: halves hold complementary l-rows of col q
    ls += __shfl_xor(ls, 32, 64);
    if (half == 0)
        Lsum[split * 32768 + h * 4096 + qw + l31] = ls;

    // partial O (unnormalized, bf16): row = h*64+kd, col = q
    bf16* Ob = Opart + split * 2097152;
#pragma unroll
    for (int r = 0; r < 16; r++) {
        int kd = (r & 3) + 8 * (r >> 2) + 4 * half;
        Ob[(h * 64 + kd) * 4096 + qw + l31]        = (bf16)oacc0[r];
        Ob[(h * 64 + 32 + kd) * 4096 + qw + l31]   = (bf16)oacc1[r];
    }
}

// ---------------- K4: combine 3 splits + V affine (stats inline) + normalize ----------------
__global__ void k_final(const bf16* __restrict__ Opart, const float* __restrict__ Lsum,
                        const float2* __restrict__ cs, const float* __restrict__ gnw,
                        const float* __restrict__ gnb, float* __restrict__ out) {
    int gid = blockIdx.x * 256 + threadIdx.x;    // 262144
    int row = gid >> 9;
    int c8  = (gid & 511) << 3;
    int h   = row >> 6;

    int g = h * 3 + 2;
    int c = threadIdx.x & 63;
    float2 v = cs[g * 64 + c];
    float s = v.x, ss = v.y;
#pragma unroll
    for (int m = 1; m < 64; m <<= 1) { s += __shfl_xor(s, m, 64); ss += __shfl_xor(ss, m, 64); }
    const float N = 262144.0f;
    float mean = s / N;
    float inv  = rsqrtf(ss / N - mean * mean + 1e-5f);
    int gi = h * 192 + 128 + (row & 63);
    float gw = gnw[gi];
    float va = inv * gw;
    float vb = gnb[gi] - mean * inv * gw;

    float o[8] = {0, 0, 0, 0, 0, 0, 0, 0};
    float l[8] = {0, 0, 0, 0, 0, 0, 0, 0};
#pragma unroll
    for (int sp = 0; sp < 3; sp++) {
        bf16x8 vv = *(const bf16x8*)(Opart + sp * 2097152 + row * 4096 + c8);
        const float* L = Lsum + sp * 32768 + h * 4096 + c8;
        float4 l0 = *(const float4*)L;
        float4 l1 = *(const float4*)(L + 4);
#pragma unroll
        for (int j = 0; j < 8; j++) o[j] += (float)vv[j];
        l[0] += l0.x; l[1] += l0.y; l[2] += l0.z; l[3] += l0.w;
        l[4] += l1.x; l[5] += l1.y; l[6] += l1.z; l[7] += l1.w;
    }
    float4 r0, r1;
    r0.x = va * o[0] / l[0] + vb; r0.y = va * o[1] / l[1] + vb;
    r0.z = va * o[2] / l[2] + vb; r0.w = va * o[3] / l[3] + vb;
    r1.x = va * o[4] / l[4] + vb; r1.y = va * o[5] / l[5] + vb;
    r1.z = va * o[6] / l[6] + vb; r1.w = va * o[7] / l[7] + vb;
    *(float4*)(out + row * 4096 + c8)     = r0;
    *(float4*)(out + row * 4096 + c8 + 4) = r1;
}

extern "C" void kernel_launch(void* const* d_in, const int* in_sizes, int n_in,
                              void* d_out, int out_size, void* d_ws, size_t ws_size,
                              hipStream_t stream) {
    const float* x      = (const float*)d_in[0];
    const float* conv_w = (const float*)d_in[1];
    const float* gn_w   = (const float*)d_in[2];
    const float* gn_b   = (const float*)d_in[3];
    float* out = (float*)d_out;
    char* ws = (char*)d_ws;

    // qkvT [0,12582912); Opart 3x4MB [12582912,25165824); Wb/xT alias Opart
    // (dead after k_conv; Opart first written by k_attn).
    bf16*   qkvT  = (bf16*) (ws);
    bf16*   Opart = (bf16*) (ws + 12582912);
    bf16*   Wb    = (bf16*) (ws + 12582912);
    bf16*   xT    = (bf16*) (ws + 13369344);
    float*  Lsum  = (float*)(ws + 25165824);        // 3*131072 B
    float*  cs    = (float*)(ws + 25559040);        // 12288 B

    hipLaunchKernelGGL(k_misc,   dim3(897),  dim3(256), 0, stream, x, conv_w, xT, Wb, cs);
    hipLaunchKernelGGL(k_conv,   dim3(1536), dim3(256), 0, stream, Wb, xT, qkvT, cs);
    hipLaunchKernelGGL(k_normqk, dim3(2048), dim3(256), 0, stream, qkvT, (const float2*)cs, gn_w, gn_b);
    hipLaunchKernelGGL(k_attn,   dim3(768),  dim3(256), 0, stream, qkvT, Opart, Lsum);
    hipLaunchKernelGGL(k_final,  dim3(1024), dim3(256), 0, stream, Opart, Lsum, (const float2*)cs, gn_w, gn_b, out);
}

// Round 10
// 141.541 us; speedup vs baseline: 1.2326x; 1.0985x over previous
//
#include <hip/hip_runtime.h>

typedef __bf16 bf16;
typedef __bf16 bf16x8 __attribute__((ext_vector_type(8)));
typedef __bf16 bf16x4 __attribute__((ext_vector_type(4)));
typedef float f32x4 __attribute__((ext_vector_type(4)));
typedef float f32x16 __attribute__((ext_vector_type(16)));

// x: [256][4096] f32, conv_w: [1536][256] f32, out: [512][4096] f32
// heads=8; channels per head: key [0:64), query [64:128), value [128:192)
// qkvT per head (786432): [QT(query) [4096][64] | KT(key) [4096][64] | V [64][4096]]
// k_conv stores RAW bf16; k_normqk normalizes Q (with log2(e)/8) and K in place;
// V affine folds into k_final: out = a_v*(sum O)/(sum L) + b_v.

#define QF 0.18033688011112042f   // log2(e)/8
#define EXPF(x) __builtin_amdgcn_exp2f(x)

union U4 { bf16x4 v; unsigned u[2]; };
union U8 { bf16x8 v; unsigned u[4]; };

// ---------------- K_misc: xpose + cast_w + zero(cs) ----------------
__global__ void k_misc(const float* __restrict__ x, const float* __restrict__ w,
                       bf16* __restrict__ xT, bf16* __restrict__ wb, float* __restrict__ cs) {
    int b = blockIdx.x;
    if (b < 512) {
        int t = b * 256 + threadIdx.x;
        int p  = t & 4095;
        int c0 = (t >> 12) * 8;
        bf16x8 o;
#pragma unroll
        for (int j = 0; j < 8; j++) o[j] = (bf16)x[(c0 + j) * 4096 + p];
        *(bf16x8*)(xT + p * 256 + c0) = o;
    } else if (b < 896) {
        int idx = ((b - 512) * 256 + threadIdx.x) * 4;
        float4 f = *(const float4*)(w + idx);
        bf16x4 o;
        o[0] = (bf16)f.x; o[1] = (bf16)f.y; o[2] = (bf16)f.z; o[3] = (bf16)f.w;
        *(bf16x4*)(wb + idx) = o;
    } else {
#pragma unroll
        for (int i = 0; i < 12; i++) cs[i * 256 + threadIdx.x] = 0.f;
    }
}

// ---------------- K1 v2: conv GEMM, LDS-staged fragments (k_attn skeleton) ----------------
// grid 1536 = 24 groups x 64 px-blocks. K-loop: 4 chunks of 64 channels,
// staged to stride-72 LDS (zero-conflict layout per R9) with reg prefetch.
__global__ __launch_bounds__(256) void k_conv(const bf16* __restrict__ Wb,
                                              const bf16* __restrict__ xT,
                                              bf16* __restrict__ qkvT,
                                              float* __restrict__ cs) {
    __shared__ __attribute__((aligned(16))) bf16 xs[64 * 72];
    __shared__ __attribute__((aligned(16))) bf16 ws2[64 * 72];
    int wid = threadIdx.x >> 6, lane = threadIdx.x & 63;
    int quad = lane >> 4, l15 = lane & 15;
    int g  = blockIdx.x % 24;
    int pb = (blockIdx.x / 24) * 64;
    int h = g / 3, sec = g % 3;          // 0=key 1=query 2=value
    int ob = g * 64;

    int srow = threadIdx.x >> 2;          // 0..63 (px for xs, o for ws2)
    int scol = (threadIdx.x & 3) * 16;    // 0/16/32/48

    f32x4 acc[4];
#pragma unroll
    for (int c = 0; c < 4; c++) acc[c] = (f32x4){0.f, 0.f, 0.f, 0.f};

    // prefetch chunk 0 (coalesced 16B loads)
    bf16x8 fx0 = *(const bf16x8*)(xT + (pb + srow) * 256 + scol);
    bf16x8 fx1 = *(const bf16x8*)(xT + (pb + srow) * 256 + scol + 8);
    bf16x8 fw0 = *(const bf16x8*)(Wb + (ob + srow) * 256 + scol);
    bf16x8 fw1 = *(const bf16x8*)(Wb + (ob + srow) * 256 + scol + 8);

    for (int c4 = 0; c4 < 4; c4++) {
        __syncthreads();
        *(bf16x8*)(xs  + srow * 72 + scol)     = fx0;
        *(bf16x8*)(xs  + srow * 72 + scol + 8) = fx1;
        *(bf16x8*)(ws2 + srow * 72 + scol)     = fw0;
        *(bf16x8*)(ws2 + srow * 72 + scol + 8) = fw1;
        __syncthreads();

        if (c4 < 3) {
            int co = (c4 + 1) * 64;
            fx0 = *(const bf16x8*)(xT + (pb + srow) * 256 + co + scol);
            fx1 = *(const bf16x8*)(xT + (pb + srow) * 256 + co + scol + 8);
            fw0 = *(const bf16x8*)(Wb + (ob + srow) * 256 + co + scol);
            fw1 = *(const bf16x8*)(Wb + (ob + srow) * 256 + co + scol + 8);
        }

#pragma unroll
        for (int k2 = 0; k2 < 2; k2++) {
            bf16x8 a = *(const bf16x8*)(ws2 + (wid * 16 + l15) * 72 + k2 * 32 + quad * 8);
#pragma unroll
            for (int c = 0; c < 4; c++) {
                bf16x8 b = *(const bf16x8*)(xs + (c * 16 + l15) * 72 + k2 * 32 + quad * 8);
                acc[c] = __builtin_amdgcn_mfma_f32_16x16x32_bf16(a, b, acc[c], 0, 0, 0);
            }
        }
    }

    // per-channel partial stats (f32 accuracy), atomics
    int ch0 = wid * 16 + quad * 4;
#pragma unroll
    for (int r = 0; r < 4; r++) {
        float sp  = acc[0][r] + acc[1][r] + acc[2][r] + acc[3][r];
        float ssp = acc[0][r] * acc[0][r] + acc[1][r] * acc[1][r]
                  + acc[2][r] * acc[2][r] + acc[3][r] * acc[3][r];
#pragma unroll
        for (int m = 1; m < 16; m <<= 1) {
            sp  += __shfl_xor(sp,  m, 64);
            ssp += __shfl_xor(ssp, m, 64);
        }
        if (l15 == 0) {
            atomicAdd(cs + (ob + ch0 + r) * 2,     sp);
            atomicAdd(cs + (ob + ch0 + r) * 2 + 1, ssp);
        }
    }

    // epilogue: LDS-transposed coalesced stores (tile aliases xs)
    __syncthreads();                      // all frag reads of xs done
    bf16* tile = xs;
    if (sec == 2) {                       // V wants [ch][px]
#pragma unroll
        for (int c = 0; c < 4; c++)
#pragma unroll
            for (int r = 0; r < 4; r++)
                tile[(ch0 + r) * 72 + c * 16 + l15] = (bf16)acc[c][r];
    } else {                              // Q/K want [px][ch]
#pragma unroll
        for (int c = 0; c < 4; c++) {
            bf16x4 o;
#pragma unroll
            for (int r = 0; r < 4; r++) o[r] = (bf16)acc[c][r];
            *(bf16x4*)(&tile[(c * 16 + l15) * 72 + ch0]) = o;
        }
    }
    __syncthreads();
    bf16* base = qkvT + h * 786432;
    int t = threadIdx.x;
    if (sec == 2) {
        bf16* V = base + 524288;
#pragma unroll
        for (int it = 0; it < 2; it++) {
            int e = it * 256 + t; int ch = e >> 3; int pxo = (e & 7) * 8;
            *(bf16x8*)(V + ch * 4096 + pb + pxo) = *(const bf16x8*)(&tile[ch * 72 + pxo]);
        }
    } else {
        bf16* dst = base + (sec == 0 ? 262144 : 0);
#pragma unroll
        for (int it = 0; it < 2; it++) {
            int e = it * 256 + t; int px = e >> 3; int cho = (e & 7) * 8;
            *(bf16x8*)(dst + (pb + px) * 64 + cho) = *(const bf16x8*)(&tile[px * 72 + cho]);
        }
    }
}

// ---------------- K2: in-place affine on Q/K (group stats inline) ----------------
__global__ __launch_bounds__(256) void k_normqk(bf16* __restrict__ qkv,
                                                const float2* __restrict__ cs,
                                                const float* __restrict__ gnw,
                                                const float* __restrict__ gnb) {
    int h    = blockIdx.x >> 8;
    int base = (blockIdx.x & 255) * 2048;            // section-pure (128 WGs per section)
    int isQ  = base < 262144;
    int g    = h * 3 + (isQ ? 1 : 0);

    int c = threadIdx.x & 63;
    float2 v = cs[g * 64 + c];
    float s = v.x, ss = v.y;
#pragma unroll
    for (int m = 1; m < 64; m <<= 1) { s += __shfl_xor(s, m, 64); ss += __shfl_xor(ss, m, 64); }
    const float N = 262144.0f;
    float mean = s / N;
    float inv  = rsqrtf(ss / N - mean * mean + 1e-5f);
    float f = isQ ? QF : 1.0f;

    int e = base + threadIdx.x * 8;
    int gc = h * 192 + (isQ ? 64 : 0) + (e & 63);
    bf16* p = qkv + h * 786432 + e;
    bf16x8 vv = *(bf16x8*)p;
    bf16x8 o;
#pragma unroll
    for (int j = 0; j < 8; j++) {
        float gw = gnw[gc + j];
        float a = inv * gw * f;
        float b = (gnb[gc + j] - mean * inv * gw) * f;
        o[j] = (bf16)(a * (float)vv[j] + b);
    }
    *(bf16x8*)p = o;
}

// helper: one 32x32 C-block (S) -> exp2 -> two PV B-fragments (named scalars only)
#define PF_BLOCK(S, PFA, PFB)                                                   \
    {                                                                           \
        float p0 = EXPF(S[0]),  p1 = EXPF(S[1]),  p2 = EXPF(S[2]),  p3 = EXPF(S[3]);   \
        float p4 = EXPF(S[4]),  p5 = EXPF(S[5]),  p6 = EXPF(S[6]),  p7 = EXPF(S[7]);   \
        float p8 = EXPF(S[8]),  p9 = EXPF(S[9]),  p10 = EXPF(S[10]), p11 = EXPF(S[11]); \
        float p12 = EXPF(S[12]), p13 = EXPF(S[13]), p14 = EXPF(S[14]), p15 = EXPF(S[15]); \
        lacc += (((p0 + p1) + (p2 + p3)) + ((p4 + p5) + (p6 + p7)))             \
              + (((p8 + p9) + (p10 + p11)) + ((p12 + p13) + (p14 + p15)));      \
        U4 lo, hi;                                                              \
        lo.v[0] = (bf16)p0;  lo.v[1] = (bf16)p1;  lo.v[2] = (bf16)p2;  lo.v[3] = (bf16)p3;  \
        hi.v[0] = (bf16)p4;  hi.v[1] = (bf16)p5;  hi.v[2] = (bf16)p6;  hi.v[3] = (bf16)p7;  \
        unsigned sa = half ? lo.u[0] : hi.u[0];                                 \
        unsigned sb = half ? lo.u[1] : hi.u[1];                                 \
        unsigned ra = (unsigned)__shfl_xor((int)sa, 32, 64);                    \
        unsigned rb = (unsigned)__shfl_xor((int)sb, 32, 64);                    \
        U8 fA;                                                                  \
        fA.u[0] = half ? ra : lo.u[0];  fA.u[1] = half ? rb : lo.u[1];          \
        fA.u[2] = half ? hi.u[0] : ra;  fA.u[3] = half ? hi.u[1] : rb;          \
        PFA = fA.v;                                                             \
        U4 lo2, hi2;                                                            \
        lo2.v[0] = (bf16)p8;  lo2.v[1] = (bf16)p9;  lo2.v[2] = (bf16)p10; lo2.v[3] = (bf16)p11; \
        hi2.v[0] = (bf16)p12; hi2.v[1] = (bf16)p13; hi2.v[2] = (bf16)p14; hi2.v[3] = (bf16)p15; \
        unsigned sc = half ? lo2.u[0] : hi2.u[0];                               \
        unsigned sd = half ? lo2.u[1] : hi2.u[1];                               \
        unsigned rc = (unsigned)__shfl_xor((int)sc, 32, 64);                    \
        unsigned rd = (unsigned)__shfl_xor((int)sd, 32, 64);                    \
        U8 fB;                                                                  \
        fB.u[0] = half ? rc : lo2.u[0];  fB.u[1] = half ? rd : lo2.u[1];        \
        fB.u[2] = half ? hi2.u[0] : rc;  fB.u[3] = half ? hi2.u[1] : rd;        \
        PFB = fB.v;                                                             \
    }

// ---------------- K3: flash attention, 32x32x16, 32q/wave, 3 waves/SIMD ----------------
// grid 768 = 8 heads x 32 q-blocks(128q) x 3 L-splits; wave owns 32 q. (unchanged R9)
__global__ __launch_bounds__(256, 3) void k_attn(const bf16* __restrict__ qkvT,
                                                 bf16* __restrict__ Opart,
                                                 float* __restrict__ Lsum) {
    int bid   = blockIdx.x;
    int h     = bid & 7;                  // XCD L2 affinity
    int qb    = (bid >> 3) & 31;
    int split = bid >> 8;                 // 0..2
    int wid = threadIdx.x >> 6, lane = threadIdx.x & 63;
    int l31 = lane & 31, half = lane >> 5;
    const bf16* QT = qkvT + h * 786432;
    const bf16* KT = QT + 262144;
    const bf16* V  = QT + 524288;
    int qw = qb * 128 + wid * 32;         // wave's 32 q

    __shared__ __attribute__((aligned(16))) bf16 Ks[64 * 72];
    __shared__ __attribute__((aligned(16))) bf16 Vs[64 * 72];

    int r0   = threadIdx.x >> 3;          // staging rows r0 and r0+32
    int koff = (threadIdx.x & 7) * 8;

    // Q B-fragments (normalized already): B[n=q][k=kd]
    bf16x8 bq[4];
#pragma unroll
    for (int ks = 0; ks < 4; ks++)
        bq[ks] = *(const bf16x8*)(QT + (qw + l31) * 64 + ks * 16 + half * 8);

    f32x16 oacc0 = (f32x16)(0.0f), oacc1 = (f32x16)(0.0f);   // kd 0-31, 32-63
    float ls = 0.f;

    int t0 = (split * 64) / 3, t1 = ((split + 1) * 64) / 3;

    bf16x8 kf0, kf1, vf0, vf1;            // register prefetch
    {
        int lb0 = t0 * 64;
        kf0 = *(const bf16x8*)(KT + (lb0 + r0) * 64 + koff);
        kf1 = *(const bf16x8*)(KT + (lb0 + r0 + 32) * 64 + koff);
        vf0 = *(const bf16x8*)(V + r0 * 4096 + lb0 + koff);
        vf1 = *(const bf16x8*)(V + (r0 + 32) * 4096 + lb0 + koff);
    }

    for (int lt = t0; lt < t1; lt++) {
        __syncthreads();
        *(bf16x8*)(Ks + r0 * 72 + koff)        = kf0;
        *(bf16x8*)(Ks + (r0 + 32) * 72 + koff) = kf1;
        *(bf16x8*)(Vs + r0 * 72 + koff)        = vf0;
        *(bf16x8*)(Vs + (r0 + 32) * 72 + koff) = vf1;
        __syncthreads();

        if (lt + 1 < t1) {
            int nb = (lt + 1) * 64;
            kf0 = *(const bf16x8*)(KT + (nb + r0) * 64 + koff);
            kf1 = *(const bf16x8*)(KT + (nb + r0 + 32) * 64 + koff);
            vf0 = *(const bf16x8*)(V + r0 * 4096 + nb + koff);
            vf1 = *(const bf16x8*)(V + (r0 + 32) * 4096 + nb + koff);
        }

        // S^T = K·Q : two 32x32 C-tiles (l 0-31, 32-63), col q = lane&31
        f32x16 s0 = (f32x16)(0.0f), s1 = (f32x16)(0.0f);
#pragma unroll
        for (int ks = 0; ks < 4; ks++) {
            s0 = __builtin_amdgcn_mfma_f32_32x32x16_bf16(
                *(const bf16x8*)(Ks + l31 * 72 + ks * 16 + half * 8), bq[ks], s0, 0, 0, 0);
            s1 = __builtin_amdgcn_mfma_f32_32x32x16_bf16(
                *(const bf16x8*)(Ks + (32 + l31) * 72 + ks * 16 + half * 8), bq[ks], s1, 0, 0, 0);
        }

        float lacc = ls;
        bf16x8 pf0, pf1, pf2, pf3;
        PF_BLOCK(s0, pf0, pf1);           // l 0..31
        PF_BLOCK(s1, pf2, pf3);           // l 32..63
        ls = lacc;

        // O[kd][q] += V·P ; V A-frags read per-use from LDS
        oacc0 = __builtin_amdgcn_mfma_f32_32x32x16_bf16(
            *(const bf16x8*)(Vs + l31 * 72 +  0 + half * 8), pf0, oacc0, 0, 0, 0);
        oacc1 = __builtin_amdgcn_mfma_f32_32x32x16_bf16(
            *(const bf16x8*)(Vs + (32 + l31) * 72 +  0 + half * 8), pf0, oacc1, 0, 0, 0);
        oacc0 = __builtin_amdgcn_mfma_f32_32x32x16_bf16(
            *(const bf16x8*)(Vs + l31 * 72 + 16 + half * 8), pf1, oacc0, 0, 0, 0);
        oacc1 = __builtin_amdgcn_mfma_f32_32x32x16_bf16(
            *(const bf16x8*)(Vs + (32 + l31) * 72 + 16 + half * 8), pf1, oacc1, 0, 0, 0);
        oacc0 = __builtin_amdgcn_mfma_f32_32x32x16_bf16(
            *(const bf16x8*)(Vs + l31 * 72 + 32 + half * 8), pf2, oacc0, 0, 0, 0);
        oacc1 = __builtin_amdgcn_mfma_f32_32x32x16_bf16(
            *(const bf16x8*)(Vs + (32 + l31) * 72 + 32 + half * 8), pf2, oacc1, 0, 0, 0);
        oacc0 = __builtin_amdgcn_mfma_f32_32x32x16_bf16(
            *(const bf16x8*)(Vs + l31 * 72 + 48 + half * 8), pf3, oacc0, 0, 0, 0);
        oacc1 = __builtin_amdgcn_mfma_f32_32x32x16_bf16(
            *(const bf16x8*)(Vs + (32 + l31) * 72 + 48 + half * 8), pf3, oacc1, 0, 0, 0);
    }

    // denominator: halves hold complementary l-rows of col q
    ls += __shfl_xor(ls, 32, 64);
    if (half == 0)
        Lsum[split * 32768 + h * 4096 + qw + l31] = ls;

    // partial O (unnormalized, bf16): row = h*64+kd, col = q
    bf16* Ob = Opart + split * 2097152;
#pragma unroll
    for (int r = 0; r < 16; r++) {
        int kd = (r & 3) + 8 * (r >> 2) + 4 * half;
        Ob[(h * 64 + kd) * 4096 + qw + l31]        = (bf16)oacc0[r];
        Ob[(h * 64 + 32 + kd) * 4096 + qw + l31]   = (bf16)oacc1[r];
    }
}

// ---------------- K4: combine 3 splits + V affine (stats inline) + normalize ----------------
__global__ void k_final(const bf16* __restrict__ Opart, const float* __restrict__ Lsum,
                        const float2* __restrict__ cs, const float* __restrict__ gnw,
                        const float* __restrict__ gnb, float* __restrict__ out) {
    int gid = blockIdx.x * 256 + threadIdx.x;    // 262144
    int row = gid >> 9;
    int c8  = (gid & 511) << 3;
    int h   = row >> 6;

    int g = h * 3 + 2;
    int c = threadIdx.x & 63;
    float2 v = cs[g * 64 + c];
    float s = v.x, ss = v.y;
#pragma unroll
    for (int m = 1; m < 64; m <<= 1) { s += __shfl_xor(s, m, 64); ss += __shfl_xor(ss, m, 64); }
    const float N = 262144.0f;
    float mean = s / N;
    float inv  = rsqrtf(ss / N - mean * mean + 1e-5f);
    int gi = h * 192 + 128 + (row & 63);
    float gw = gnw[gi];
    float va = inv * gw;
    float vb = gnb[gi] - mean * inv * gw;

    float o[8] = {0, 0, 0, 0, 0, 0, 0, 0};
    float l[8] = {0, 0, 0, 0, 0, 0, 0, 0};
#pragma unroll
    for (int sp = 0; sp < 3; sp++) {
        bf16x8 vv = *(const bf16x8*)(Opart + sp * 2097152 + row * 4096 + c8);
        const float* L = Lsum + sp * 32768 + h * 4096 + c8;
        float4 l0 = *(const float4*)L;
        float4 l1 = *(const float4*)(L + 4);
#pragma unroll
        for (int j = 0; j < 8; j++) o[j] += (float)vv[j];
        l[0] += l0.x; l[1] += l0.y; l[2] += l0.z; l[3] += l0.w;
        l[4] += l1.x; l[5] += l1.y; l[6] += l1.z; l[7] += l1.w;
    }
    float4 r0, r1;
    r0.x = va * o[0] / l[0] + vb; r0.y = va * o[1] / l[1] + vb;
    r0.z = va * o[2] / l[2] + vb; r0.w = va * o[3] / l[3] + vb;
    r1.x = va * o[4] / l[4] + vb; r1.y = va * o[5] / l[5] + vb;
    r1.z = va * o[6] / l[6] + vb; r1.w = va * o[7] / l[7] + vb;
    *(float4*)(out + row * 4096 + c8)     = r0;
    *(float4*)(out + row * 4096 + c8 + 4) = r1;
}

extern "C" void kernel_launch(void* const* d_in, const int* in_sizes, int n_in,
                              void* d_out, int out_size, void* d_ws, size_t ws_size,
                              hipStream_t stream) {
    const float* x      = (const float*)d_in[0];
    const float* conv_w = (const float*)d_in[1];
    const float* gn_w   = (const float*)d_in[2];
    const float* gn_b   = (const float*)d_in[3];
    float* out = (float*)d_out;
    char* ws = (char*)d_ws;

    // qkvT [0,12582912); Opart 3x4MB [12582912,25165824); Wb/xT alias Opart
    // (dead after k_conv; Opart first written by k_attn).
    bf16*   qkvT  = (bf16*) (ws);
    bf16*   Opart = (bf16*) (ws + 12582912);
    bf16*   Wb    = (bf16*) (ws + 12582912);
    bf16*   xT    = (bf16*) (ws + 13369344);
    float*  Lsum  = (float*)(ws + 25165824);        // 3*131072 B
    float*  cs    = (float*)(ws + 25559040);        // 12288 B

    hipLaunchKernelGGL(k_misc,   dim3(897),  dim3(256), 0, stream, x, conv_w, xT, Wb, cs);
    hipLaunchKernelGGL(k_conv,   dim3(1536), dim3(256), 0, stream, Wb, xT, qkvT, cs);
    hipLaunchKernelGGL(k_normqk, dim3(2048), dim3(256), 0, stream, qkvT, (const float2*)cs, gn_w, gn_b);
    hipLaunchKernelGGL(k_attn,   dim3(768),  dim3(256), 0, stream, qkvT, Opart, Lsum);
    hipLaunchKernelGGL(k_final,  dim3(1024), dim3(256), 0, stream, Opart, Lsum, (const float2*)cs, gn_w, gn_b, out);
}

// Round 11
// 140.226 us; speedup vs baseline: 1.2442x; 1.0094x over previous
//
#include <hip/hip_runtime.h>

typedef __bf16 bf16;
typedef __bf16 bf16x8 __attribute__((ext_vector_type(8)));
typedef __bf16 bf16x4 __attribute__((ext_vector_type(4)));
typedef float f32x4 __attribute__((ext_vector_type(4)));
typedef float f32x16 __attribute__((ext_vector_type(16)));

// x: [256][4096] f32, conv_w: [1536][256] f32, out: [512][4096] f32
// heads=8; channels per head: key [0:64), query [64:128), value [128:192)
// qkvT per head (786432): [QT(query) [4096][64] | KT(key) [4096][64] | V [64][4096]]
// k_conv stores RAW bf16; k_normqk normalizes Q (with log2(e)/8) and K in place;
// V affine folds into k_final: out = a_v*(sum O)/(sum L) + b_v.

#define QF 0.18033688011112042f   // log2(e)/8
#define EXPF(x) __builtin_amdgcn_exp2f(x)

union U4 { bf16x4 v; unsigned u[2]; };
union U8 { bf16x8 v; unsigned u[4]; };

// ---------------- K_misc: xpose + cast_w + zero(cs) ----------------
__global__ void k_misc(const float* __restrict__ x, const float* __restrict__ w,
                       bf16* __restrict__ xT, bf16* __restrict__ wb, float* __restrict__ cs) {
    int b = blockIdx.x;
    if (b < 512) {
        int t = b * 256 + threadIdx.x;
        int p  = t & 4095;
        int c0 = (t >> 12) * 8;
        bf16x8 o;
#pragma unroll
        for (int j = 0; j < 8; j++) o[j] = (bf16)x[(c0 + j) * 4096 + p];
        *(bf16x8*)(xT + p * 256 + c0) = o;
    } else if (b < 896) {
        int idx = ((b - 512) * 256 + threadIdx.x) * 4;
        float4 f = *(const float4*)(w + idx);
        bf16x4 o;
        o[0] = (bf16)f.x; o[1] = (bf16)f.y; o[2] = (bf16)f.z; o[3] = (bf16)f.w;
        *(bf16x4*)(wb + idx) = o;
    } else {
#pragma unroll
        for (int i = 0; i < 12; i++) cs[i * 256 + threadIdx.x] = 0.f;
    }
}

// ---------------- K1: conv GEMM, LDS-staged fragments ----------------
__global__ __launch_bounds__(256) void k_conv(const bf16* __restrict__ Wb,
                                              const bf16* __restrict__ xT,
                                              bf16* __restrict__ qkvT,
                                              float* __restrict__ cs) {
    __shared__ __attribute__((aligned(16))) bf16 xs[64 * 72];
    __shared__ __attribute__((aligned(16))) bf16 ws2[64 * 72];
    int wid = threadIdx.x >> 6, lane = threadIdx.x & 63;
    int quad = lane >> 4, l15 = lane & 15;
    int g  = blockIdx.x % 24;
    int pb = (blockIdx.x / 24) * 64;
    int h = g / 3, sec = g % 3;          // 0=key 1=query 2=value
    int ob = g * 64;

    int srow = threadIdx.x >> 2;          // 0..63
    int scol = (threadIdx.x & 3) * 16;    // 0/16/32/48

    f32x4 acc[4];
#pragma unroll
    for (int c = 0; c < 4; c++) acc[c] = (f32x4){0.f, 0.f, 0.f, 0.f};

    bf16x8 fx0 = *(const bf16x8*)(xT + (pb + srow) * 256 + scol);
    bf16x8 fx1 = *(const bf16x8*)(xT + (pb + srow) * 256 + scol + 8);
    bf16x8 fw0 = *(const bf16x8*)(Wb + (ob + srow) * 256 + scol);
    bf16x8 fw1 = *(const bf16x8*)(Wb + (ob + srow) * 256 + scol + 8);

    for (int c4 = 0; c4 < 4; c4++) {
        __syncthreads();
        *(bf16x8*)(xs  + srow * 72 + scol)     = fx0;
        *(bf16x8*)(xs  + srow * 72 + scol + 8) = fx1;
        *(bf16x8*)(ws2 + srow * 72 + scol)     = fw0;
        *(bf16x8*)(ws2 + srow * 72 + scol + 8) = fw1;
        __syncthreads();

        if (c4 < 3) {
            int co = (c4 + 1) * 64;
            fx0 = *(const bf16x8*)(xT + (pb + srow) * 256 + co + scol);
            fx1 = *(const bf16x8*)(xT + (pb + srow) * 256 + co + scol + 8);
            fw0 = *(const bf16x8*)(Wb + (ob + srow) * 256 + co + scol);
            fw1 = *(const bf16x8*)(Wb + (ob + srow) * 256 + co + scol + 8);
        }

#pragma unroll
        for (int k2 = 0; k2 < 2; k2++) {
            bf16x8 a = *(const bf16x8*)(ws2 + (wid * 16 + l15) * 72 + k2 * 32 + quad * 8);
#pragma unroll
            for (int c = 0; c < 4; c++) {
                bf16x8 b = *(const bf16x8*)(xs + (c * 16 + l15) * 72 + k2 * 32 + quad * 8);
                acc[c] = __builtin_amdgcn_mfma_f32_16x16x32_bf16(a, b, acc[c], 0, 0, 0);
            }
        }
    }

    int ch0 = wid * 16 + quad * 4;
#pragma unroll
    for (int r = 0; r < 4; r++) {
        float sp  = acc[0][r] + acc[1][r] + acc[2][r] + acc[3][r];
        float ssp = acc[0][r] * acc[0][r] + acc[1][r] * acc[1][r]
                  + acc[2][r] * acc[2][r] + acc[3][r] * acc[3][r];
#pragma unroll
        for (int m = 1; m < 16; m <<= 1) {
            sp  += __shfl_xor(sp,  m, 64);
            ssp += __shfl_xor(ssp, m, 64);
        }
        if (l15 == 0) {
            atomicAdd(cs + (ob + ch0 + r) * 2,     sp);
            atomicAdd(cs + (ob + ch0 + r) * 2 + 1, ssp);
        }
    }

    __syncthreads();
    bf16* tile = xs;
    if (sec == 2) {                       // V wants [ch][px]
#pragma unroll
        for (int c = 0; c < 4; c++)
#pragma unroll
            for (int r = 0; r < 4; r++)
                tile[(ch0 + r) * 72 + c * 16 + l15] = (bf16)acc[c][r];
    } else {                              // Q/K want [px][ch]
#pragma unroll
        for (int c = 0; c < 4; c++) {
            bf16x4 o;
#pragma unroll
            for (int r = 0; r < 4; r++) o[r] = (bf16)acc[c][r];
            *(bf16x4*)(&tile[(c * 16 + l15) * 72 + ch0]) = o;
        }
    }
    __syncthreads();
    bf16* base = qkvT + h * 786432;
    int t = threadIdx.x;
    if (sec == 2) {
        bf16* V = base + 524288;
#pragma unroll
        for (int it = 0; it < 2; it++) {
            int e = it * 256 + t; int ch = e >> 3; int pxo = (e & 7) * 8;
            *(bf16x8*)(V + ch * 4096 + pb + pxo) = *(const bf16x8*)(&tile[ch * 72 + pxo]);
        }
    } else {
        bf16* dst = base + (sec == 0 ? 262144 : 0);
#pragma unroll
        for (int it = 0; it < 2; it++) {
            int e = it * 256 + t; int px = e >> 3; int cho = (e & 7) * 8;
            *(bf16x8*)(dst + (pb + px) * 64 + cho) = *(const bf16x8*)(&tile[px * 72 + cho]);
        }
    }
}

// ---------------- K2: in-place affine on Q/K (group stats inline) ----------------
__global__ __launch_bounds__(256) void k_normqk(bf16* __restrict__ qkv,
                                                const float2* __restrict__ cs,
                                                const float* __restrict__ gnw,
                                                const float* __restrict__ gnb) {
    int h    = blockIdx.x >> 8;
    int base = (blockIdx.x & 255) * 2048;
    int isQ  = base < 262144;
    int g    = h * 3 + (isQ ? 1 : 0);

    int c = threadIdx.x & 63;
    float2 v = cs[g * 64 + c];
    float s = v.x, ss = v.y;
#pragma unroll
    for (int m = 1; m < 64; m <<= 1) { s += __shfl_xor(s, m, 64); ss += __shfl_xor(ss, m, 64); }
    const float N = 262144.0f;
    float mean = s / N;
    float inv  = rsqrtf(ss / N - mean * mean + 1e-5f);
    float f = isQ ? QF : 1.0f;

    int e = base + threadIdx.x * 8;
    int gc = h * 192 + (isQ ? 64 : 0) + (e & 63);
    bf16* p = qkv + h * 786432 + e;
    bf16x8 vv = *(bf16x8*)p;
    bf16x8 o;
#pragma unroll
    for (int j = 0; j < 8; j++) {
        float gw = gnw[gc + j];
        float a = inv * gw * f;
        float b = (gnb[gc + j] - mean * inv * gw) * f;
        o[j] = (bf16)(a * (float)vv[j] + b);
    }
    *(bf16x8*)p = o;
}

// helper: one 32x32 C-block (S) -> exp2 -> two PV B-fragments (named scalars only)
#define PF_BLOCK(S, PFA, PFB)                                                   \
    {                                                                           \
        float p0 = EXPF(S[0]),  p1 = EXPF(S[1]),  p2 = EXPF(S[2]),  p3 = EXPF(S[3]);   \
        float p4 = EXPF(S[4]),  p5 = EXPF(S[5]),  p6 = EXPF(S[6]),  p7 = EXPF(S[7]);   \
        float p8 = EXPF(S[8]),  p9 = EXPF(S[9]),  p10 = EXPF(S[10]), p11 = EXPF(S[11]); \
        float p12 = EXPF(S[12]), p13 = EXPF(S[13]), p14 = EXPF(S[14]), p15 = EXPF(S[15]); \
        lacc += (((p0 + p1) + (p2 + p3)) + ((p4 + p5) + (p6 + p7)))             \
              + (((p8 + p9) + (p10 + p11)) + ((p12 + p13) + (p14 + p15)));      \
        U4 lo, hi;                                                              \
        lo.v[0] = (bf16)p0;  lo.v[1] = (bf16)p1;  lo.v[2] = (bf16)p2;  lo.v[3] = (bf16)p3;  \
        hi.v[0] = (bf16)p4;  hi.v[1] = (bf16)p5;  hi.v[2] = (bf16)p6;  hi.v[3] = (bf16)p7;  \
        unsigned sa = half ? lo.u[0] : hi.u[0];                                 \
        unsigned sb = half ? lo.u[1] : hi.u[1];                                 \
        unsigned ra = (unsigned)__shfl_xor((int)sa, 32, 64);                    \
        unsigned rb = (unsigned)__shfl_xor((int)sb, 32, 64);                    \
        U8 fA;                                                                  \
        fA.u[0] = half ? ra : lo.u[0];  fA.u[1] = half ? rb : lo.u[1];          \
        fA.u[2] = half ? hi.u[0] : ra;  fA.u[3] = half ? hi.u[1] : rb;          \
        PFA = fA.v;                                                             \
        U4 lo2, hi2;                                                            \
        lo2.v[0] = (bf16)p8;  lo2.v[1] = (bf16)p9;  lo2.v[2] = (bf16)p10; lo2.v[3] = (bf16)p11; \
        hi2.v[0] = (bf16)p12; hi2.v[1] = (bf16)p13; hi2.v[2] = (bf16)p14; hi2.v[3] = (bf16)p15; \
        unsigned sc = half ? lo2.u[0] : hi2.u[0];                               \
        unsigned sd = half ? lo2.u[1] : hi2.u[1];                               \
        unsigned rc = (unsigned)__shfl_xor((int)sc, 32, 64);                    \
        unsigned rd = (unsigned)__shfl_xor((int)sd, 32, 64);                    \
        U8 fB;                                                                  \
        fB.u[0] = half ? rc : lo2.u[0];  fB.u[1] = half ? rd : lo2.u[1];        \
        fB.u[2] = half ? hi2.u[0] : rc;  fB.u[3] = half ? hi2.u[1] : rd;        \
        PFB = fB.v;                                                             \
    }

// ---------------- K3: flash attention, 32x32x16, 32q/wave, 4 waves/SIMD ----------------
// grid 1024 = 8 heads x 32 q-blocks(128q) x 4 L-splits; wave owns 32 q.
__global__ __launch_bounds__(256, 4) void k_attn(const bf16* __restrict__ qkvT,
                                                 bf16* __restrict__ Opart,
                                                 float* __restrict__ Lsum) {
    int bid   = blockIdx.x;
    int h     = bid & 7;                  // XCD L2 affinity
    int qb    = (bid >> 3) & 31;
    int split = bid >> 8;                 // 0..3
    int wid = threadIdx.x >> 6, lane = threadIdx.x & 63;
    int l31 = lane & 31, half = lane >> 5;
    const bf16* QT = qkvT + h * 786432;
    const bf16* KT = QT + 262144;
    const bf16* V  = QT + 524288;
    int qw = qb * 128 + wid * 32;         // wave's 32 q

    __shared__ __attribute__((aligned(16))) bf16 Ks[64 * 72];
    __shared__ __attribute__((aligned(16))) bf16 Vs[64 * 72];

    int r0   = threadIdx.x >> 3;          // staging rows r0 and r0+32
    int koff = (threadIdx.x & 7) * 8;

    // Q B-fragments (normalized already): B[n=q][k=kd]
    bf16x8 bq[4];
#pragma unroll
    for (int ks = 0; ks < 4; ks++)
        bq[ks] = *(const bf16x8*)(QT + (qw + l31) * 64 + ks * 16 + half * 8);

    f32x16 oacc0 = (f32x16)(0.0f), oacc1 = (f32x16)(0.0f);   // kd 0-31, 32-63
    float ls = 0.f;

    int t0 = split * 16, t1 = t0 + 16;

    bf16x8 kf0, kf1, vf0, vf1;            // register prefetch
    {
        int lb0 = t0 * 64;
        kf0 = *(const bf16x8*)(KT + (lb0 + r0) * 64 + koff);
        kf1 = *(const bf16x8*)(KT + (lb0 + r0 + 32) * 64 + koff);
        vf0 = *(const bf16x8*)(V + r0 * 4096 + lb0 + koff);
        vf1 = *(const bf16x8*)(V + (r0 + 32) * 4096 + lb0 + koff);
    }

    for (int lt = t0; lt < t1; lt++) {
        __syncthreads();
        *(bf16x8*)(Ks + r0 * 72 + koff)        = kf0;
        *(bf16x8*)(Ks + (r0 + 32) * 72 + koff) = kf1;
        *(bf16x8*)(Vs + r0 * 72 + koff)        = vf0;
        *(bf16x8*)(Vs + (r0 + 32) * 72 + koff) = vf1;
        __syncthreads();

        if (lt + 1 < t1) {
            int nb = (lt + 1) * 64;
            kf0 = *(const bf16x8*)(KT + (nb + r0) * 64 + koff);
            kf1 = *(const bf16x8*)(KT + (nb + r0 + 32) * 64 + koff);
            vf0 = *(const bf16x8*)(V + r0 * 4096 + nb + koff);
            vf1 = *(const bf16x8*)(V + (r0 + 32) * 4096 + nb + koff);
        }

        // S^T = K·Q : two 32x32 C-tiles (l 0-31, 32-63), col q = lane&31
        f32x16 s0 = (f32x16)(0.0f), s1 = (f32x16)(0.0f);
#pragma unroll
        for (int ks = 0; ks < 4; ks++) {
            s0 = __builtin_amdgcn_mfma_f32_32x32x16_bf16(
                *(const bf16x8*)(Ks + l31 * 72 + ks * 16 + half * 8), bq[ks], s0, 0, 0, 0);
            s1 = __builtin_amdgcn_mfma_f32_32x32x16_bf16(
                *(const bf16x8*)(Ks + (32 + l31) * 72 + ks * 16 + half * 8), bq[ks], s1, 0, 0, 0);
        }

        float lacc = ls;
        bf16x8 pf0, pf1, pf2, pf3;
        PF_BLOCK(s0, pf0, pf1);           // l 0..31
        PF_BLOCK(s1, pf2, pf3);           // l 32..63
        ls = lacc;

        // O[kd][q] += V·P ; V A-frags read per-use from LDS
        oacc0 = __builtin_amdgcn_mfma_f32_32x32x16_bf16(
            *(const bf16x8*)(Vs + l31 * 72 +  0 + half * 8), pf0, oacc0, 0, 0, 0);
        oacc1 = __builtin_amdgcn_mfma_f32_32x32x16_bf16(
            *(const bf16x8*)(Vs + (32 + l31) * 72 +  0 + half * 8), pf0, oacc1, 0, 0, 0);
        oacc0 = __builtin_amdgcn_mfma_f32_32x32x16_bf16(
            *(const bf16x8*)(Vs + l31 * 72 + 16 + half * 8), pf1, oacc0, 0, 0, 0);
        oacc1 = __builtin_amdgcn_mfma_f32_32x32x16_bf16(
            *(const bf16x8*)(Vs + (32 + l31) * 72 + 16 + half * 8), pf1, oacc1, 0, 0, 0);
        oacc0 = __builtin_amdgcn_mfma_f32_32x32x16_bf16(
            *(const bf16x8*)(Vs + l31 * 72 + 32 + half * 8), pf2, oacc0, 0, 0, 0);
        oacc1 = __builtin_amdgcn_mfma_f32_32x32x16_bf16(
            *(const bf16x8*)(Vs + (32 + l31) * 72 + 32 + half * 8), pf2, oacc1, 0, 0, 0);
        oacc0 = __builtin_amdgcn_mfma_f32_32x32x16_bf16(
            *(const bf16x8*)(Vs + l31 * 72 + 48 + half * 8), pf3, oacc0, 0, 0, 0);
        oacc1 = __builtin_amdgcn_mfma_f32_32x32x16_bf16(
            *(const bf16x8*)(Vs + (32 + l31) * 72 + 48 + half * 8), pf3, oacc1, 0, 0, 0);
    }

    // denominator: halves hold complementary l-rows of col q
    ls += __shfl_xor(ls, 32, 64);
    if (half == 0)
        Lsum[split * 32768 + h * 4096 + qw + l31] = ls;

    // partial O (unnormalized, bf16): row = h*64+kd, col = q
    bf16* Ob = Opart + split * 2097152;
#pragma unroll
    for (int r = 0; r < 16; r++) {
        int kd = (r & 3) + 8 * (r >> 2) + 4 * half;
        Ob[(h * 64 + kd) * 4096 + qw + l31]        = (bf16)oacc0[r];
        Ob[(h * 64 + 32 + kd) * 4096 + qw + l31]   = (bf16)oacc1[r];
    }
}

// ---------------- K4: combine 4 splits + V affine (stats inline) + normalize ----------------
__global__ void k_final(const bf16* __restrict__ Opart, const float* __restrict__ Lsum,
                        const float2* __restrict__ cs, const float* __restrict__ gnw,
                        const float* __restrict__ gnb, float* __restrict__ out) {
    int gid = blockIdx.x * 256 + threadIdx.x;    // 262144
    int row = gid >> 9;
    int c8  = (gid & 511) << 3;
    int h   = row >> 6;

    int g = h * 3 + 2;
    int c = threadIdx.x & 63;
    float2 v = cs[g * 64 + c];
    float s = v.x, ss = v.y;
#pragma unroll
    for (int m = 1; m < 64; m <<= 1) { s += __shfl_xor(s, m, 64); ss += __shfl_xor(ss, m, 64); }
    const float N = 262144.0f;
    float mean = s / N;
    float inv  = rsqrtf(ss / N - mean * mean + 1e-5f);
    int gi = h * 192 + 128 + (row & 63);
    float gw = gnw[gi];
    float va = inv * gw;
    float vb = gnb[gi] - mean * inv * gw;

    float o[8] = {0, 0, 0, 0, 0, 0, 0, 0};
    float l[8] = {0, 0, 0, 0, 0, 0, 0, 0};
#pragma unroll
    for (int sp = 0; sp < 4; sp++) {
        bf16x8 vv = *(const bf16x8*)(Opart + sp * 2097152 + row * 4096 + c8);
        const float* L = Lsum + sp * 32768 + h * 4096 + c8;
        float4 l0 = *(const float4*)L;
        float4 l1 = *(const float4*)(L + 4);
#pragma unroll
        for (int j = 0; j < 8; j++) o[j] += (float)vv[j];
        l[0] += l0.x; l[1] += l0.y; l[2] += l0.z; l[3] += l0.w;
        l[4] += l1.x; l[5] += l1.y; l[6] += l1.z; l[7] += l1.w;
    }
    float4 r0, r1;
    r0.x = va * o[0] / l[0] + vb; r0.y = va * o[1] / l[1] + vb;
    r0.z = va * o[2] / l[2] + vb; r0.w = va * o[3] / l[3] + vb;
    r1.x = va * o[4] / l[4] + vb; r1.y = va * o[5] / l[5] + vb;
    r1.z = va * o[6] / l[6] + vb; r1.w = va * o[7] / l[7] + vb;
    *(float4*)(out + row * 4096 + c8)     = r0;
    *(float4*)(out + row * 4096 + c8 + 4) = r1;
}

extern "C" void kernel_launch(void* const* d_in, const int* in_sizes, int n_in,
                              void* d_out, int out_size, void* d_ws, size_t ws_size,
                              hipStream_t stream) {
    const float* x      = (const float*)d_in[0];
    const float* conv_w = (const float*)d_in[1];
    const float* gn_w   = (const float*)d_in[2];
    const float* gn_b   = (const float*)d_in[3];
    float* out = (float*)d_out;
    char* ws = (char*)d_ws;

    // qkvT [0,12582912); Opart 4x4MB [12582912,29360128); Wb/xT alias Opart
    // (dead after k_conv; Opart first written by k_attn).
    bf16*   qkvT  = (bf16*) (ws);
    bf16*   Opart = (bf16*) (ws + 12582912);
    bf16*   Wb    = (bf16*) (ws + 12582912);
    bf16*   xT    = (bf16*) (ws + 13369344);
    float*  Lsum  = (float*)(ws + 29360128);        // 4*131072 B
    float*  cs    = (float*)(ws + 29884416);        // 12288 B

    hipLaunchKernelGGL(k_misc,   dim3(897),  dim3(256), 0, stream, x, conv_w, xT, Wb, cs);
    hipLaunchKernelGGL(k_conv,   dim3(1536), dim3(256), 0, stream, Wb, xT, qkvT, cs);
    hipLaunchKernelGGL(k_normqk, dim3(2048), dim3(256), 0, stream, qkvT, (const float2*)cs, gn_w, gn_b);
    hipLaunchKernelGGL(k_attn,   dim3(1024), dim3(256), 0, stream, qkvT, Opart, Lsum);
    hipLaunchKernelGGL(k_final,  dim3(1024), dim3(256), 0, stream, Opart, Lsum, (const float2*)cs, gn_w, gn_b, out);
}